// Round 12
// baseline (258.001 us; speedup 1.0000x reference)
//
#include <hip/hip_runtime.h>
#include <hip/hip_bf16.h>
#include <hip/hip_cooperative_groups.h>
#include <math.h>

namespace cg = cooperative_groups;

#define BB 64
#define NLAYER 2

typedef __attribute__((ext_vector_type(8))) short bfrag;
typedef __attribute__((ext_vector_type(4))) float f4_t;

__device__ __forceinline__ float dot4(float4 a, float4 b, float acc) {
    acc = fmaf(a.x, b.x, acc);
    acc = fmaf(a.y, b.y, acc);
    acc = fmaf(a.z, b.z, acc);
    acc = fmaf(a.w, b.w, acc);
    return acc;
}

__device__ __forceinline__ ushort f2bf(float f) {
    uint32_t u = __float_as_uint(f);
    uint32_t r = (u + 0x7FFFu + ((u >> 16) & 1u)) >> 16;
    return (ushort)r;
}
__device__ __forceinline__ float bf2f(ushort u) {
    return __uint_as_float(((uint32_t)u) << 16);
}

__device__ __forceinline__ void gll16(const ushort* g, ushort* l) {
    __builtin_amdgcn_global_load_lds(
        (const __attribute__((address_space(1))) void*)g,
        (__attribute__((address_space(3))) void*)l, 16, 0, 0);
}

struct MegaParams {
    const float *x, *nv, *ev;
    const float *fp_w, *fp_b, *fp_g, *fp_beta;
    const float *qkv_w, *qkv_b, *aow, *aob, *ln1g, *ln1b;
    const float *f1w, *f1b, *f2w, *f2b, *ln2g, *ln2b;
    const float *outw, *outb;
    const float *muw1, *mub1, *mug, *mubt, *muw2, *mub2;
    const float *lvw1, *lvb1, *lvg, *lvbt, *lvw2, *lvb2;
    float* out;
    float* stats;
    ushort *wh_bf, *At, *Xt, *o_bf, *f1_bf, *qb, *kb, *vtb, *yT, *wbf;
};

// ---------------------------------------------------------------------------
// Phase device functions (identical numerics to the R10 kernels).
// ---------------------------------------------------------------------------
__device__ void d_cvt(int tid, int g, const MegaParams& p) {
    const size_t idx = (size_t)g * 2048 + tid * 8;
    const float* src;
    size_t base;
    if (g < 32)       { src = p.fp_w;  base = 0; }
    else if (g < 224) { src = p.qkv_w; base = 65536; }
    else if (g < 288) { src = p.aow;   base = 458752; }
    else if (g < 416) { src = p.f1w;   base = 589824; }
    else if (g < 544) { src = p.f2w;   base = 851968; }
    else              { src = p.outw;  base = 1114112; }
    const float4* s4 = reinterpret_cast<const float4*>(src + (idx - base));
    float4 a = s4[0], b = s4[1];
    bfrag o;
    o[0] = (short)f2bf(a.x); o[1] = (short)f2bf(a.y);
    o[2] = (short)f2bf(a.z); o[3] = (short)f2bf(a.w);
    o[4] = (short)f2bf(b.x); o[5] = (short)f2bf(b.y);
    o[6] = (short)f2bf(b.z); o[7] = (short)f2bf(b.w);
    *reinterpret_cast<bfrag*>(p.wbf + idx) = o;
}

__device__ void d_xpose(char* smch, int tid, int k0, int i0, int b,
                        const MegaParams& p) {
    float (*TA)[65] = (float(*)[65])smch;
    float (*TX)[65] = (float(*)[65])(smch + 64 * 65 * 4);
    const size_t bb = (size_t)b * 65536;
    const int lr = tid >> 4, lc = (tid & 15) * 4;
#pragma unroll
    for (int l = 0; l < 4; ++l) {
        const int row = lr + l * 16;
        const size_t gidx = bb + (size_t)(k0 + row) * 256 + i0 + lc;
        float4 n4 = *reinterpret_cast<const float4*>(p.nv + gidx);
        float4 e4 = *reinterpret_cast<const float4*>(p.ev + gidx);
        float4 x4 = *reinterpret_cast<const float4*>(p.x + gidx);
        TA[row][lc] = 0.5f * (n4.x + e4.x);
        TA[row][lc + 1] = 0.5f * (n4.y + e4.y);
        TA[row][lc + 2] = 0.5f * (n4.z + e4.z);
        TA[row][lc + 3] = 0.5f * (n4.w + e4.w);
        TX[row][lc] = x4.x;
        TX[row][lc + 1] = x4.y;
        TX[row][lc + 2] = x4.z;
        TX[row][lc + 3] = x4.w;
    }
    __syncthreads();
    const int i = tid & 63, kk = (tid >> 6) * 16;
    bfrag a0, a1, x0, x1;
#pragma unroll
    for (int e = 0; e < 8; ++e) {
        a0[e] = (short)f2bf(TA[kk + e][i]);
        a1[e] = (short)f2bf(TA[kk + 8 + e][i]);
        x0[e] = (short)f2bf(TX[kk + e][i]);
        x1[e] = (short)f2bf(TX[kk + 8 + e][i]);
    }
    const size_t o = bb + (size_t)(i0 + i) * 256 + k0 + kk;
    *reinterpret_cast<bfrag*>(p.At + o) = a0;
    *reinterpret_cast<bfrag*>(p.At + o + 8) = a1;
    *reinterpret_cast<bfrag*>(p.Xt + o) = x0;
    *reinterpret_cast<bfrag*>(p.Xt + o + 8) = x1;
    __syncthreads();
}

#define MM97_STAGE(SRC, LDS, KSTRIDE)                                        \
    {                                                                        \
        _Pragma("unroll")                                                    \
        for (int c = 0; c < 4; ++c) {                                        \
            const int rr = (w << 5) + (c << 3) + (lane >> 3);                \
            gll16(SRC + (size_t)rr * (KSTRIDE) + k0 + ((lane & 7) << 3),     \
                  LDS + (((w << 5) + (c << 3)) << 6));                       \
        }                                                                    \
    }

#define MM97_COMPUTE()                                                       \
    _Pragma("unroll")                                                        \
    for (int ks = 0; ks < 2; ++ks) {                                         \
        const int kb = ks * 32 + fq * 8;                                     \
        bfrag af[4], bfv[4];                                                 \
        _Pragma("unroll")                                                    \
        for (int fm = 0; fm < 4; ++fm)                                       \
            af[fm] = *reinterpret_cast<const bfrag*>(                        \
                &As[((wm * 64 + fm * 16 + fr) << 6) + kb]);                  \
        _Pragma("unroll")                                                    \
        for (int fn = 0; fn < 4; ++fn)                                       \
            bfv[fn] = *reinterpret_cast<const bfrag*>(                       \
                &Bs[((wn * 64 + fn * 16 + fr) << 6) + kb]);                  \
        _Pragma("unroll")                                                    \
        for (int fm = 0; fm < 4; ++fm)                                       \
            _Pragma("unroll")                                                \
            for (int fn = 0; fn < 4; ++fn)                                   \
                acc[fm][fn] = __builtin_amdgcn_mfma_f32_16x16x32_bf16(       \
                    bfv[fn], af[fm], acc[fm][fn], 0, 0, 0);                  \
    }

template <int EPI, bool WF32, bool WBF>
__device__ void d_mm97(char* smch, int tid, int m0, int n0, size_t z,
                       const ushort* A, const ushort* B, const float* bias,
                       float* C, ushort* Cb, int K, int N,
                       size_t aStr, size_t bStr, size_t cStr) {
    ushort* As = (ushort*)smch;
    ushort* Bs = As + 8192;
    const int w = tid >> 6, lane = tid & 63;
    const int wm = w >> 1, wn = w & 1;
    const int fr = lane & 15, fq = lane >> 4;

    const ushort* aB = A + z * aStr + (size_t)m0 * K;
    const ushort* bB = B + z * bStr + (size_t)n0 * K;

    f4_t acc[4][4];
#pragma unroll
    for (int i = 0; i < 4; ++i)
#pragma unroll
        for (int j = 0; j < 4; ++j) acc[i][j] = (f4_t)0.f;

    for (int k0 = 0; k0 < K; k0 += 64) {
        MM97_STAGE(aB, As, K)
        MM97_STAGE(bB, Bs, K)
        __syncthreads();
        MM97_COMPUTE()
        __syncthreads();
    }

#pragma unroll
    for (int fn = 0; fn < 4; ++fn) {
        const int col0 = n0 + wn * 64 + fn * 16 + fq * 4;
        float4 bv = make_float4(0.f, 0.f, 0.f, 0.f);
        if (bias != nullptr)
            bv = *reinterpret_cast<const float4*>(&bias[col0]);
#pragma unroll
        for (int fm = 0; fm < 4; ++fm) {
            const int row = m0 + wm * 64 + fm * 16 + fr;
            float v0 = acc[fm][fn][0] + bv.x;
            float v1 = acc[fm][fn][1] + bv.y;
            float v2 = acc[fm][fn][2] + bv.z;
            float v3 = acc[fm][fn][3] + bv.w;
            if (EPI == 2) {
                v0 = fmaxf(v0, 0.f); v1 = fmaxf(v1, 0.f);
                v2 = fmaxf(v2, 0.f); v3 = fmaxf(v3, 0.f);
            }
            const size_t o = cStr * z + (size_t)row * N + col0;
            if (WF32) {
                float4 fv = {v0, v1, v2, v3};
                *reinterpret_cast<float4*>(&C[o]) = fv;
            }
            if (WBF) {
                ushort4 uv;
                uv.x = f2bf(v0); uv.y = f2bf(v1);
                uv.z = f2bf(v2); uv.w = f2bf(v3);
                *reinterpret_cast<ushort4*>(&Cb[o]) = uv;
            }
        }
    }
}

__device__ void d_mmqkv97(char* smch, int tid, int m0, int n0,
                          const ushort* A, const ushort* B, const float* bias,
                          ushort* qb, ushort* kbuf, ushort* vtb) {
    ushort* As = (ushort*)smch;
    ushort* Bs = As + 8192;
    const int w = tid >> 6, lane = tid & 63;
    const int wm = w >> 1, wn = w & 1;
    const int fr = lane & 15, fq = lane >> 4;
    const int K = 256;

    const ushort* aB = A + (size_t)m0 * K;
    const ushort* bB = B + (size_t)n0 * K;

    f4_t acc[4][4];
#pragma unroll
    for (int i = 0; i < 4; ++i)
#pragma unroll
        for (int j = 0; j < 4; ++j) acc[i][j] = (f4_t)0.f;

    for (int k0 = 0; k0 < K; k0 += 64) {
        MM97_STAGE(aB, As, K)
        MM97_STAGE(bB, Bs, K)
        __syncthreads();
        MM97_COMPUTE()
        __syncthreads();
    }

    const int sec = n0 >> 8;
#pragma unroll
    for (int fn = 0; fn < 4; ++fn) {
        const int col0 = n0 + wn * 64 + fn * 16 + fq * 4;
        const int hd = (col0 >> 5) & 7, dq = col0 & 31;
        const float4 bv = *reinterpret_cast<const float4*>(&bias[col0]);
#pragma unroll
        for (int fm = 0; fm < 4; ++fm) {
            const int row = m0 + wm * 64 + fm * 16 + fr;
            const int b = row >> 8, t = row & 255;
            const size_t bh = (size_t)b * 8 + hd;
            float v0 = acc[fm][fn][0] + bv.x;
            float v1 = acc[fm][fn][1] + bv.y;
            float v2 = acc[fm][fn][2] + bv.z;
            float v3 = acc[fm][fn][3] + bv.w;
            if (sec < 2) {
                ushort4 uv;
                uv.x = f2bf(v0); uv.y = f2bf(v1);
                uv.z = f2bf(v2); uv.w = f2bf(v3);
                ushort* dst = (sec == 0 ? qb : kbuf) + (bh * 256 + t) * 32 + dq;
                *reinterpret_cast<ushort4*>(dst) = uv;
            } else {
                ushort* dst = vtb + (bh * 32 + dq) * 256 + t;
                dst[0] = f2bf(v0);
                dst[256] = f2bf(v1);
                dst[512] = f2bf(v2);
                dst[768] = f2bf(v3);
            }
        }
    }
}

__device__ void d_corr97(char* smch, int tid, int m0, int n0, size_t z,
                         const ushort* A, const float* stats, float* C) {
    ushort* As = (ushort*)smch;
    ushort* Bs = As + 8192;
    const int w = tid >> 6, lane = tid & 63;
    const int wm = w >> 1, wn = w & 1;
    const int fr = lane & 15, fq = lane >> 4;
    const int K = 256;

    const ushort* aB = A + z * 65536 + (size_t)m0 * K;
    const ushort* bB = A + z * 65536 + (size_t)n0 * K;

    f4_t acc[4][4];
#pragma unroll
    for (int i = 0; i < 4; ++i)
#pragma unroll
        for (int j = 0; j < 4; ++j) acc[i][j] = (f4_t)0.f;

    for (int k0 = 0; k0 < K; k0 += 64) {
        MM97_STAGE(aB, As, K)
        MM97_STAGE(bB, Bs, K)
        __syncthreads();
        MM97_COMPUTE()
        __syncthreads();
    }

    const float* st = stats + z * 512;
#pragma unroll
    for (int fn = 0; fn < 4; ++fn) {
        const int col0 = n0 + wn * 64 + fn * 16 + fq * 4;
        const float4 muj = *reinterpret_cast<const float4*>(&st[col0]);
        const float4 isj = *reinterpret_cast<const float4*>(&st[256 + col0]);
#pragma unroll
        for (int fm = 0; fm < 4; ++fm) {
            const int row = m0 + wm * 64 + fm * 16 + fr;
            const float mui = st[row];
            const float isi = st[256 + row] * (1.f / 255.f);
            float v0 = (acc[fm][fn][0] - 256.f * mui * muj.x) * isi * isj.x;
            float v1 = (acc[fm][fn][1] - 256.f * mui * muj.y) * isi * isj.y;
            float v2 = (acc[fm][fn][2] - 256.f * mui * muj.z) * isi * isj.z;
            float v3 = (acc[fm][fn][3] - 256.f * mui * muj.w) * isi * isj.w;
            if (v0 != v0) v0 = 0.f;
            if (v1 != v1) v1 = 0.f;
            if (v2 != v2) v2 = 0.f;
            if (v3 != v3) v3 = 0.f;
            v0 = fminf(1.f, fmaxf(-1.f, v0));
            v1 = fminf(1.f, fmaxf(-1.f, v1));
            v2 = fminf(1.f, fmaxf(-1.f, v2));
            v3 = fminf(1.f, fmaxf(-1.f, v3));
            float4 fv = {v0, v1, v2, v3};
            *reinterpret_cast<float4*>(
                &C[z * 65536 + (size_t)row * 256 + col0]) = fv;
        }
    }
}

template <int ACT, bool RES>
__device__ void d_mmln(char* smch, int tid, int m0,
                       const ushort* A, const ushort* W, const float* bias,
                       const ushort* res, const float* g, const float* bt,
                       ushort* outb, int K) {
    ushort* As = (ushort*)smch;                 // 32*72
    ushort* Bs = As + 2304;                     // 256*72
    float* redS = (float*)(smch + 41472);       // [32][4]
    float* redQ = redS + 128;                   // [32][4]
    const int w = tid >> 6, lane = tid & 63;
    const int fr = lane & 15, fq = lane >> 4;

    const int arow = tid >> 3, akc = (tid & 7) * 8;
    const ushort* aS = A + (size_t)(m0 + arow) * K + akc;
    ushort* aD = &As[arow * 72 + akc];
    const int brow = tid >> 1, bkc = (tid & 1) * 32;
    const ushort* bS0 = W + (size_t)brow * K + bkc;
    const ushort* bS1 = W + (size_t)(brow + 128) * K + bkc;
    ushort* bD0 = &Bs[brow * 72 + bkc];
    ushort* bD1 = &Bs[(brow + 128) * 72 + bkc];

    f4_t acc[2][4];
#pragma unroll
    for (int i = 0; i < 2; ++i)
#pragma unroll
        for (int j = 0; j < 4; ++j) acc[i][j] = (f4_t)0.f;

    bfrag ra, rb0, rb1, rb2, rb3, rc0, rc1, rc2, rc3;
    {
        ra = *reinterpret_cast<const bfrag*>(aS);
        const bfrag* bp0 = reinterpret_cast<const bfrag*>(bS0);
        rb0 = bp0[0]; rb1 = bp0[1]; rb2 = bp0[2]; rb3 = bp0[3];
        const bfrag* bp1 = reinterpret_cast<const bfrag*>(bS1);
        rc0 = bp1[0]; rc1 = bp1[1]; rc2 = bp1[2]; rc3 = bp1[3];
    }

    for (int k0 = 0; k0 < K; k0 += 64) {
        *reinterpret_cast<bfrag*>(aD) = ra;
        reinterpret_cast<bfrag*>(bD0)[0] = rb0;
        reinterpret_cast<bfrag*>(bD0)[1] = rb1;
        reinterpret_cast<bfrag*>(bD0)[2] = rb2;
        reinterpret_cast<bfrag*>(bD0)[3] = rb3;
        reinterpret_cast<bfrag*>(bD1)[0] = rc0;
        reinterpret_cast<bfrag*>(bD1)[1] = rc1;
        reinterpret_cast<bfrag*>(bD1)[2] = rc2;
        reinterpret_cast<bfrag*>(bD1)[3] = rc3;
        __syncthreads();
        if (k0 + 64 < K) {
            ra = *reinterpret_cast<const bfrag*>(aS + k0 + 64);
            const bfrag* bp0 = reinterpret_cast<const bfrag*>(bS0 + k0 + 64);
            rb0 = bp0[0]; rb1 = bp0[1]; rb2 = bp0[2]; rb3 = bp0[3];
            const bfrag* bp1 = reinterpret_cast<const bfrag*>(bS1 + k0 + 64);
            rc0 = bp1[0]; rc1 = bp1[1]; rc2 = bp1[2]; rc3 = bp1[3];
        }
#pragma unroll
        for (int ks = 0; ks < 2; ++ks) {
            const int kb = ks * 32 + fq * 8;
            bfrag af[2], bf[4];
#pragma unroll
            for (int fm = 0; fm < 2; ++fm)
                af[fm] = *reinterpret_cast<const bfrag*>(
                    &As[(fm * 16 + fr) * 72 + kb]);
#pragma unroll
            for (int fn = 0; fn < 4; ++fn)
                bf[fn] = *reinterpret_cast<const bfrag*>(
                    &Bs[(w * 64 + fn * 16 + fr) * 72 + kb]);
#pragma unroll
            for (int fm = 0; fm < 2; ++fm)
#pragma unroll
                for (int fn = 0; fn < 4; ++fn)
                    acc[fm][fn] = __builtin_amdgcn_mfma_f32_16x16x32_bf16(
                        bf[fn], af[fm], acc[fm][fn], 0, 0, 0);
        }
        __syncthreads();
    }

#pragma unroll
    for (int fn = 0; fn < 4; ++fn) {
        const int col0 = w * 64 + fn * 16 + fq * 4;
        const float4 bv = *reinterpret_cast<const float4*>(&bias[col0]);
#pragma unroll
        for (int fm = 0; fm < 2; ++fm) {
            const int row = fm * 16 + fr;
            float r0 = 0.f, r1 = 0.f, r2 = 0.f, r3 = 0.f;
            if (RES) {
                ushort4 r4 = *reinterpret_cast<const ushort4*>(
                    &res[(size_t)(m0 + row) * 256 + col0]);
                r0 = bf2f(r4.x); r1 = bf2f(r4.y);
                r2 = bf2f(r4.z); r3 = bf2f(r4.w);
            }
            acc[fm][fn][0] += bv.x + r0;
            acc[fm][fn][1] += bv.y + r1;
            acc[fm][fn][2] += bv.z + r2;
            acc[fm][fn][3] += bv.w + r3;
        }
    }
#pragma unroll
    for (int fm = 0; fm < 2; ++fm) {
        float s = 0.f, q = 0.f;
#pragma unroll
        for (int fn = 0; fn < 4; ++fn)
#pragma unroll
            for (int j = 0; j < 4; ++j) {
                const float v = acc[fm][fn][j];
                s += v;
                q += v * v;
            }
        s += __shfl_xor(s, 16); q += __shfl_xor(q, 16);
        s += __shfl_xor(s, 32); q += __shfl_xor(q, 32);
        if (fq == 0) {
            redS[(fm * 16 + fr) * 4 + w] = s;
            redQ[(fm * 16 + fr) * 4 + w] = q;
        }
    }
    __syncthreads();
#pragma unroll
    for (int fm = 0; fm < 2; ++fm) {
        const int row = fm * 16 + fr;
        const float S = redS[row * 4] + redS[row * 4 + 1] + redS[row * 4 + 2] + redS[row * 4 + 3];
        const float Q = redQ[row * 4] + redQ[row * 4 + 1] + redQ[row * 4 + 2] + redQ[row * 4 + 3];
        const float mean = S * (1.f / 256.f);
        const float var = Q * (1.f / 256.f) - mean * mean;
        const float rstd = rsqrtf(fmaxf(var, 0.f) + 1e-5f);
        const size_t rowoff = (size_t)(m0 + row) * 256;
#pragma unroll
        for (int fn = 0; fn < 4; ++fn) {
            const int col0 = w * 64 + fn * 16 + fq * 4;
            const float4 g4 = *reinterpret_cast<const float4*>(&g[col0]);
            const float4 b4 = *reinterpret_cast<const float4*>(&bt[col0]);
            float v0 = (acc[fm][fn][0] - mean) * rstd * g4.x + b4.x;
            float v1 = (acc[fm][fn][1] - mean) * rstd * g4.y + b4.y;
            float v2 = (acc[fm][fn][2] - mean) * rstd * g4.z + b4.z;
            float v3 = (acc[fm][fn][3] - mean) * rstd * g4.w + b4.w;
            if (ACT == 1) {
                v0 = v0 >= 0.f ? v0 : 0.1f * v0;
                v1 = v1 >= 0.f ? v1 : 0.1f * v1;
                v2 = v2 >= 0.f ? v2 : 0.1f * v2;
                v3 = v3 >= 0.f ? v3 : 0.1f * v3;
            }
            ushort4 uv;
            uv.x = f2bf(v0); uv.y = f2bf(v1);
            uv.z = f2bf(v2); uv.w = f2bf(v3);
            *reinterpret_cast<ushort4*>(&outb[rowoff + col0]) = uv;
        }
    }
    __syncthreads();
}

__device__ void d_attn3(char* smch, int tid, int hd, int b,
                        const ushort* qb, const ushort* kbuf,
                        const ushort* vtb, ushort* o) {
    ushort (*Ps)[64][40] = (ushort(*)[64][40])smch;
    const size_t bh = (size_t)b * 8 + hd;
    const int w = tid >> 6, lane = tid & 63;
    const int fr = lane & 15, fq = lane >> 4;

    const ushort* qB = qb + bh * 8192;
    const ushort* kB = kbuf + bh * 8192;
    const ushort* vB = vtb + bh * 8192;

    const int q0 = w * 64;
    bfrag qf[4];
#pragma unroll
    for (int fm = 0; fm < 4; ++fm)
        qf[fm] = *reinterpret_cast<const bfrag*>(
            qB + (size_t)(q0 + fm * 16 + fr) * 32 + fq * 8);

    f4_t oacc[4][2];
    float rs[4][4];
#pragma unroll
    for (int fm = 0; fm < 4; ++fm) {
        oacc[fm][0] = (f4_t)0.f;
        oacc[fm][1] = (f4_t)0.f;
#pragma unroll
        for (int j = 0; j < 4; ++j) rs[fm][j] = 0.f;
    }
    const f4_t zero4 = (f4_t)0.f;
    const float qsl = 0.17677669529663687f * 1.4426950408889634f;

    for (int kt = 0; kt < 8; ++kt) {
        bfrag kf0 = *reinterpret_cast<const bfrag*>(
            kB + (size_t)(kt * 32 + fr) * 32 + fq * 8);
        bfrag kf1 = *reinterpret_cast<const bfrag*>(
            kB + (size_t)(kt * 32 + 16 + fr) * 32 + fq * 8);
        f4_t s0[4], s1[4];
#pragma unroll
        for (int fm = 0; fm < 4; ++fm) {
            s0[fm] = __builtin_amdgcn_mfma_f32_16x16x32_bf16(qf[fm], kf0, zero4, 0, 0, 0);
            s1[fm] = __builtin_amdgcn_mfma_f32_16x16x32_bf16(qf[fm], kf1, zero4, 0, 0, 0);
        }
#pragma unroll
        for (int fm = 0; fm < 4; ++fm) {
#pragma unroll
            for (int j = 0; j < 4; ++j) {
                const int row = fm * 16 + fq * 4 + j;
                ushort u0 = f2bf(exp2f(s0[fm][j] * qsl));
                ushort u1 = f2bf(exp2f(s1[fm][j] * qsl));
                Ps[w][row][fr] = u0;
                Ps[w][row][16 + fr] = u1;
                rs[fm][j] += bf2f(u0) + bf2f(u1);
            }
        }
        bfrag vf0 = *reinterpret_cast<const bfrag*>(
            vB + (size_t)fr * 256 + kt * 32 + fq * 8);
        bfrag vf1 = *reinterpret_cast<const bfrag*>(
            vB + (size_t)(16 + fr) * 256 + kt * 32 + fq * 8);
        bfrag pf[4];
#pragma unroll
        for (int fm = 0; fm < 4; ++fm)
            pf[fm] = *reinterpret_cast<const bfrag*>(&Ps[w][fm * 16 + fr][fq * 8]);
#pragma unroll
        for (int fm = 0; fm < 4; ++fm) {
            oacc[fm][0] = __builtin_amdgcn_mfma_f32_16x16x32_bf16(pf[fm], vf0, oacc[fm][0], 0, 0, 0);
            oacc[fm][1] = __builtin_amdgcn_mfma_f32_16x16x32_bf16(pf[fm], vf1, oacc[fm][1], 0, 0, 0);
        }
    }

#pragma unroll
    for (int fm = 0; fm < 4; ++fm)
#pragma unroll
        for (int j = 0; j < 4; ++j) {
            float r = rs[fm][j];
            r += __shfl_xor(r, 1);
            r += __shfl_xor(r, 2);
            r += __shfl_xor(r, 4);
            r += __shfl_xor(r, 8);
            rs[fm][j] = 1.f / r;
        }
    ushort* ob = o + (size_t)b * 65536 + hd * 32;
#pragma unroll
    for (int fm = 0; fm < 4; ++fm) {
        const int qrow = q0 + fm * 16 + fq * 4;
#pragma unroll
        for (int j = 0; j < 4; ++j) {
            const float inv = rs[fm][j];
            ob[(size_t)(qrow + j) * 256 + fr] = f2bf(oacc[fm][0][j] * inv);
            ob[(size_t)(qrow + j) * 256 + 16 + fr] = f2bf(oacc[fm][1][j] * inv);
        }
    }
}

__device__ void d_rowstats(int tid, int rx, int b, const ushort* yT,
                           float* stats) {
    const int r = rx * 64 + (tid >> 2);
    const int part = tid & 3;
    const ushort* row = yT + (size_t)b * 65536 + (size_t)r * 256 + part * 64;
    float s = 0.f, q = 0.f;
#pragma unroll
    for (int i = 0; i < 8; ++i) {
        bfrag v = reinterpret_cast<const bfrag*>(row)[i];
#pragma unroll
        for (int e = 0; e < 8; ++e) {
            float f = bf2f((ushort)v[e]);
            s += f;
            q += f * f;
        }
    }
    s += __shfl_xor(s, 1); q += __shfl_xor(q, 1);
    s += __shfl_xor(s, 2); q += __shfl_xor(q, 2);
    if (part == 0) {
        const float mean = s * (1.f / 256.f);
        const float var = (q - s * mean) * (1.f / 255.f);
        const float stdv = sqrtf(fmaxf(var, 0.f));
        stats[b * 512 + r] = mean;
        stats[b * 512 + 256 + r] = 1.f / (stdv + 1e-8f);
    }
}

__device__ void d_poolhead(char* smch, int tid, int b, const MegaParams& p) {
    float* pooled = (float*)smch;
    float* rS = pooled + 256;
    float* rQ = rS + 4;
    float* t1 = rQ + 4;

    {
        const ushort* hb = p.wh_bf + (size_t)b * 65536 + tid;
        float s = 0.f;
        for (int t = 0; t < 256; ++t) s += bf2f(hb[(size_t)t * 256]);
        pooled[tid] = s * (1.f / 256.f);
    }
    __syncthreads();

    const int hd = tid >> 7, u = tid & 127;
    const float* w1 = hd ? p.lvw1 : p.muw1;
    const float* b1 = hd ? p.lvb1 : p.mub1;
    float a = b1[u];
    const float4* w1v = reinterpret_cast<const float4*>(w1 + (size_t)u * 256);
#pragma unroll 4
    for (int k4 = 0; k4 < 64; ++k4) {
        float4 wv = w1v[k4];
        float4 pv = *reinterpret_cast<const float4*>(&pooled[k4 * 4]);
        a = dot4(pv, wv, a);
    }
    float s = a, q = a * a;
#pragma unroll
    for (int m = 1; m < 64; m <<= 1) {
        s += __shfl_xor(s, m);
        q += __shfl_xor(q, m);
    }
    if ((tid & 63) == 0) { rS[tid >> 6] = s; rQ[tid >> 6] = q; }
    __syncthreads();
    {
        const float* g = hd ? p.lvg : p.mug;
        const float* bt = hd ? p.lvbt : p.mubt;
        const float S = rS[hd * 2] + rS[hd * 2 + 1];
        const float Q = rQ[hd * 2] + rQ[hd * 2 + 1];
        const float mean = S * (1.f / 128.f);
        const float var = Q * (1.f / 128.f) - mean * mean;
        const float rstd = rsqrtf(fmaxf(var, 0.f) + 1e-5f);
        float v = (a - mean) * rstd * g[u] + bt[u];
        v = v >= 0.f ? v : 0.1f * v;
        t1[hd * 128 + u] = v;
    }
    __syncthreads();
    if (tid < 128) {
        const int h2 = tid >> 6, ou = tid & 63;
        const float* w2 = h2 ? p.lvw2 : p.muw2;
        const float* b2 = h2 ? p.lvb2 : p.mub2;
        float o = b2[ou];
        const float* w2r = w2 + (size_t)ou * 128;
#pragma unroll 4
        for (int c = 0; c < 128; ++c) o = fmaf(t1[h2 * 128 + c], w2r[c], o);
        p.out[h2 * 4096 + b * 64 + ou] = o;
    }
    __syncthreads();
}

// ---------------------------------------------------------------------------
// Cooperative megakernel: grid-stride phases + 15 grid syncs.
// ---------------------------------------------------------------------------
__global__ __launch_bounds__(256) void k_mega(MegaParams p) {
    __shared__ __align__(16) char sm[43008];
    cg::grid_group grid = cg::this_grid();
    const int tid = threadIdx.x;
    const int gs = gridDim.x;

    for (int vb = blockIdx.x; vb < 1600; vb += gs) {
        if (vb < 576) d_cvt(tid, vb, p);
        else {
            const int q = vb - 576;
            d_xpose(sm, tid, (q & 3) * 64, ((q >> 2) & 3) * 64, q >> 4, p);
        }
    }
    grid.sync();
    for (int vb = blockIdx.x; vb < 256; vb += gs)
        d_mm97<0, false, true>(sm, tid, ((vb >> 1) & 1) * 128, (vb & 1) * 128,
                               (size_t)(vb >> 2), p.At, p.Xt, nullptr, nullptr,
                               p.o_bf, 256, 256, 65536, 65536, 65536);
    grid.sync();
    for (int vb = blockIdx.x; vb < 512; vb += gs)
        d_mmln<1, false>(sm, tid, vb * 32, p.o_bf, p.wbf, p.fp_b, nullptr,
                         p.fp_g, p.fp_beta, p.wh_bf, 256);
    grid.sync();

    for (int l = 0; l < NLAYER; ++l) {
        const ushort* wq = p.wbf + 65536 + (size_t)l * 196608;
        const ushort* wa = p.wbf + 458752 + (size_t)l * 65536;
        const ushort* w1 = p.wbf + 589824 + (size_t)l * 131072;
        const ushort* w2 = p.wbf + 851968 + (size_t)l * 131072;
        for (int vb = blockIdx.x; vb < 768; vb += gs)
            d_mmqkv97(sm, tid, (vb & 127) * 128, (vb >> 7) * 128,
                      p.wh_bf, wq, p.qkv_b + l * 768, p.qb, p.kb, p.vtb);
        grid.sync();
        for (int vb = blockIdx.x; vb < 512; vb += gs)
            d_attn3(sm, tid, vb & 7, vb >> 3, p.qb, p.kb, p.vtb, p.o_bf);
        grid.sync();
        for (int vb = blockIdx.x; vb < 512; vb += gs)
            d_mmln<0, true>(sm, tid, vb * 32, p.o_bf, wa, p.aob + l * 256,
                            p.wh_bf, p.ln1g + l * 256, p.ln1b + l * 256,
                            p.wh_bf, 256);
        grid.sync();
        for (int vb = blockIdx.x; vb < 512; vb += gs)
            d_mm97<2, false, true>(sm, tid, (vb & 127) * 128, (vb >> 7) * 128,
                                   0, p.wh_bf, w1, p.f1b + l * 512, nullptr,
                                   p.f1_bf, 256, 512, 0, 0, 0);
        grid.sync();
        for (int vb = blockIdx.x; vb < 512; vb += gs)
            d_mmln<0, true>(sm, tid, vb * 32, p.f1_bf, w2, p.f2b + l * 256,
                            p.wh_bf, p.ln2g + l * 256, p.ln2b + l * 256,
                            p.wh_bf, 512);
        grid.sync();
    }

    for (int vb = blockIdx.x; vb < 256; vb += gs)
        d_mm97<0, false, true>(sm, tid, ((vb >> 1) & 1) * 128, (vb & 1) * 128,
                               (size_t)(vb >> 2), p.wbf + 1114112, p.wh_bf,
                               nullptr, nullptr, p.yT, 256, 256, 0, 65536,
                               65536);
    grid.sync();
    for (int vb = blockIdx.x; vb < 256; vb += gs)
        d_rowstats(tid, vb & 3, vb >> 2, p.yT, p.stats);
    grid.sync();
    for (int vb = blockIdx.x; vb < 320; vb += gs) {
        if (vb < 256)
            d_corr97(sm, tid, ((vb >> 1) & 1) * 128, (vb & 1) * 128,
                     (size_t)(vb >> 2), p.yT, p.stats, p.out + 8192);
        else
            d_poolhead(sm, tid, vb - 256, p);
    }
}

// ---------------------------------------------------------------------------
// Fallback wrapper kernels (same device functions, R10-style grids).
// ---------------------------------------------------------------------------
__global__ __launch_bounds__(256) void kw_prep(MegaParams p) {
    __shared__ __align__(16) char sm[33280];
    const int vb = blockIdx.x;
    if (vb < 576) d_cvt(threadIdx.x, vb, p);
    else {
        const int q = vb - 576;
        d_xpose(sm, threadIdx.x, (q & 3) * 64, ((q >> 2) & 3) * 64, q >> 4, p);
    }
}
__global__ __launch_bounds__(256) void kw_bmm(MegaParams p) {
    __shared__ __align__(16) char sm[32768];
    const int vb = blockIdx.x;
    d_mm97<0, false, true>(sm, threadIdx.x, ((vb >> 1) & 1) * 128,
                           (vb & 1) * 128, (size_t)(vb >> 2), p.At, p.Xt,
                           nullptr, nullptr, p.o_bf, 256, 256, 65536, 65536,
                           65536);
}
__global__ __launch_bounds__(256) void kw_ln0(MegaParams p) {
    __shared__ __align__(16) char sm[42496];
    d_mmln<1, false>(sm, threadIdx.x, blockIdx.x * 32, p.o_bf, p.wbf, p.fp_b,
                     nullptr, p.fp_g, p.fp_beta, p.wh_bf, 256);
}
__global__ __launch_bounds__(256) void kw_qkv(MegaParams p, int l) {
    __shared__ __align__(16) char sm[32768];
    const int vb = blockIdx.x;
    d_mmqkv97(sm, threadIdx.x, (vb & 127) * 128, (vb >> 7) * 128, p.wh_bf,
              p.wbf + 65536 + (size_t)l * 196608, p.qkv_b + l * 768,
              p.qb, p.kb, p.vtb);
}
__global__ __launch_bounds__(256) void kw_attn(MegaParams p) {
    __shared__ __align__(16) char sm[20480];
    d_attn3(sm, threadIdx.x, blockIdx.x & 7, blockIdx.x >> 3, p.qb, p.kb,
            p.vtb, p.o_bf);
}
__global__ __launch_bounds__(256) void kw_ln1(MegaParams p, int l) {
    __shared__ __align__(16) char sm[42496];
    d_mmln<0, true>(sm, threadIdx.x, blockIdx.x * 32, p.o_bf,
                    p.wbf + 458752 + (size_t)l * 65536, p.aob + l * 256,
                    p.wh_bf, p.ln1g + l * 256, p.ln1b + l * 256, p.wh_bf, 256);
}
__global__ __launch_bounds__(256) void kw_ffn1(MegaParams p, int l) {
    __shared__ __align__(16) char sm[32768];
    const int vb = blockIdx.x;
    d_mm97<2, false, true>(sm, threadIdx.x, (vb & 127) * 128, (vb >> 7) * 128,
                           0, p.wh_bf, p.wbf + 589824 + (size_t)l * 131072,
                           p.f1b + l * 512, nullptr, p.f1_bf, 256, 512, 0, 0,
                           0);
}
__global__ __launch_bounds__(256) void kw_ln2(MegaParams p, int l) {
    __shared__ __align__(16) char sm[42496];
    d_mmln<0, true>(sm, threadIdx.x, blockIdx.x * 32, p.f1_bf,
                    p.wbf + 851968 + (size_t)l * 131072, p.f2b + l * 256,
                    p.wh_bf, p.ln2g + l * 256, p.ln2b + l * 256, p.wh_bf, 512);
}
__global__ __launch_bounds__(256) void kw_yt(MegaParams p) {
    __shared__ __align__(16) char sm[32768];
    const int vb = blockIdx.x;
    d_mm97<0, false, true>(sm, threadIdx.x, ((vb >> 1) & 1) * 128,
                           (vb & 1) * 128, (size_t)(vb >> 2),
                           p.wbf + 1114112, p.wh_bf, nullptr, nullptr, p.yT,
                           256, 256, 0, 65536, 65536);
}
__global__ __launch_bounds__(256) void kw_rstats(MegaParams p) {
    d_rowstats(threadIdx.x, blockIdx.x & 3, blockIdx.x >> 2, p.yT, p.stats);
}
__global__ __launch_bounds__(256) void kw_corrpool(MegaParams p) {
    __shared__ __align__(16) char sm[32768];
    const int vb = blockIdx.x;
    if (vb < 256)
        d_corr97(sm, threadIdx.x, ((vb >> 1) & 1) * 128, (vb & 1) * 128,
                 (size_t)(vb >> 2), p.yT, p.stats, p.out + 8192);
    else
        d_poolhead(sm, threadIdx.x, vb - 256, p);
}

// ---------------------------------------------------------------------------
extern "C" void kernel_launch(void* const* d_in, const int* in_sizes, int n_in,
                              void* d_out, int out_size, void* d_ws, size_t ws_size,
                              hipStream_t stream) {
    float* ws = (float*)d_ws;
    ushort* ub = (ushort*)(ws + 32768);

    MegaParams p;
    p.x = (const float*)d_in[0];
    p.nv = (const float*)d_in[1];
    p.ev = (const float*)d_in[2];
    p.fp_w = (const float*)d_in[3];
    p.fp_b = (const float*)d_in[4];
    p.fp_g = (const float*)d_in[5];
    p.fp_beta = (const float*)d_in[6];
    p.qkv_w = (const float*)d_in[7];
    p.qkv_b = (const float*)d_in[8];
    p.aow = (const float*)d_in[9];
    p.aob = (const float*)d_in[10];
    p.ln1g = (const float*)d_in[11];
    p.ln1b = (const float*)d_in[12];
    p.f1w = (const float*)d_in[13];
    p.f1b = (const float*)d_in[14];
    p.f2w = (const float*)d_in[15];
    p.f2b = (const float*)d_in[16];
    p.ln2g = (const float*)d_in[17];
    p.ln2b = (const float*)d_in[18];
    p.outw = (const float*)d_in[19];
    p.outb = (const float*)d_in[20];
    p.muw1 = (const float*)d_in[21];
    p.mub1 = (const float*)d_in[22];
    p.mug = (const float*)d_in[23];
    p.mubt = (const float*)d_in[24];
    p.muw2 = (const float*)d_in[25];
    p.mub2 = (const float*)d_in[26];
    p.lvw1 = (const float*)d_in[27];
    p.lvb1 = (const float*)d_in[28];
    p.lvg = (const float*)d_in[29];
    p.lvbt = (const float*)d_in[30];
    p.lvw2 = (const float*)d_in[31];
    p.lvb2 = (const float*)d_in[32];
    p.out = (float*)d_out;
    p.stats = ws;
    p.wh_bf = ub;
    p.At = ub + 4194304;
    p.Xt = ub + 8388608;
    p.o_bf = ub + 16777216;
    p.f1_bf = ub + 20971520;
    p.qb = ub + 29360128;
    p.kb = ub + 33554432;
    p.vtb = ub + 37748736;
    p.yT = ub + 41943040;
    p.wbf = ub + 46137344;

    // Try cooperative megakernel with a validated grid size.
    int dev = 0;
    (void)hipGetDevice(&dev);
    int cus = 0;
    (void)hipDeviceGetAttribute(&cus, hipDeviceAttributeMultiprocessorCount, dev);
    int nb = 0;
    (void)hipOccupancyMaxActiveBlocksPerMultiprocessor(
        &nb, (const void*)k_mega, 256, 0);
    int grid = (nb > 0 && cus > 0) ? nb * cus : 0;
    if (grid > 512) grid = 512;

    hipError_t err = hipErrorUnknown;
    if (grid >= 64) {
        void* args[] = {&p};
        err = hipLaunchCooperativeKernel(reinterpret_cast<void*>(k_mega),
                                         dim3(grid), dim3(256), args, 0,
                                         stream);
    }
    (void)hipGetLastError();
    if (err == hipSuccess) return;

    // Fallback: 16-launch multi-kernel path (identical numerics).
    kw_prep<<<1600, 256, 0, stream>>>(p);
    kw_bmm<<<256, 256, 0, stream>>>(p);
    kw_ln0<<<512, 256, 0, stream>>>(p);
    for (int l = 0; l < NLAYER; ++l) {
        kw_qkv<<<768, 256, 0, stream>>>(p, l);
        kw_attn<<<512, 256, 0, stream>>>(p);
        kw_ln1<<<512, 256, 0, stream>>>(p, l);
        kw_ffn1<<<512, 256, 0, stream>>>(p, l);
        kw_ln2<<<512, 256, 0, stream>>>(p, l);
    }
    kw_yt<<<256, 256, 0, stream>>>(p);
    kw_rstats<<<256, 256, 0, stream>>>(p);
    kw_corrpool<<<320, 256, 0, stream>>>(p);
}

// Round 13
// 229.211 us; speedup vs baseline: 1.1256x; 1.1256x over previous
//
#include <hip/hip_runtime.h>
#include <hip/hip_bf16.h>
#include <math.h>

#define BB 64
#define NLAYER 2

typedef __attribute__((ext_vector_type(8))) short bfrag;
typedef __attribute__((ext_vector_type(4))) float f4_t;

__device__ __forceinline__ float dot4(float4 a, float4 b, float acc) {
    acc = fmaf(a.x, b.x, acc);
    acc = fmaf(a.y, b.y, acc);
    acc = fmaf(a.z, b.z, acc);
    acc = fmaf(a.w, b.w, acc);
    return acc;
}

// fp32 -> bf16 round-to-nearest-even
__device__ __forceinline__ ushort f2bf(float f) {
    uint32_t u = __float_as_uint(f);
    uint32_t r = (u + 0x7FFFu + ((u >> 16) & 1u)) >> 16;
    return (ushort)r;
}
__device__ __forceinline__ float bf2f(ushort u) {
    return __uint_as_float(((uint32_t)u) << 16);
}

__device__ __forceinline__ void gll16(const ushort* g, ushort* l) {
    __builtin_amdgcn_global_load_lds(
        (const __attribute__((address_space(1))) void*)g,
        (__attribute__((address_space(3))) void*)l, 16, 0, 0);
}

// ---------------------------------------------------------------------------
// Fused prep: blocks 0..575 convert weights fp32->bf16; blocks 576..1599
// transpose+convert message-passing inputs.
// ---------------------------------------------------------------------------
__global__ __launch_bounds__(256) void k_prep(
    const float* __restrict__ x, const float* __restrict__ nv,
    const float* __restrict__ ev,
    const float* __restrict__ fp_w, const float* __restrict__ qkv_w,
    const float* __restrict__ aow, const float* __restrict__ f1w,
    const float* __restrict__ f2w, const float* __restrict__ outw,
    ushort* __restrict__ wbf, ushort* __restrict__ At,
    ushort* __restrict__ Xt) {
    const int vb = blockIdx.x;
    const int tid = threadIdx.x;
    if (vb < 576) {
        const int g = vb;
        const size_t idx = (size_t)g * 2048 + tid * 8;
        const float* src;
        size_t base;
        if (g < 32)       { src = fp_w;  base = 0; }
        else if (g < 224) { src = qkv_w; base = 65536; }
        else if (g < 288) { src = aow;   base = 458752; }
        else if (g < 416) { src = f1w;   base = 589824; }
        else if (g < 544) { src = f2w;   base = 851968; }
        else              { src = outw;  base = 1114112; }
        const float4* s4 = reinterpret_cast<const float4*>(src + (idx - base));
        float4 a = s4[0], b = s4[1];
        bfrag o;
        o[0] = (short)f2bf(a.x); o[1] = (short)f2bf(a.y);
        o[2] = (short)f2bf(a.z); o[3] = (short)f2bf(a.w);
        o[4] = (short)f2bf(b.x); o[5] = (short)f2bf(b.y);
        o[6] = (short)f2bf(b.z); o[7] = (short)f2bf(b.w);
        *reinterpret_cast<bfrag*>(wbf + idx) = o;
        return;
    }
    __shared__ float TA[64][65];
    __shared__ float TX[64][65];
    const int q = vb - 576;
    const int k0 = (q & 3) * 64, i0 = ((q >> 2) & 3) * 64, b = q >> 4;
    const size_t bb = (size_t)b * 65536;
    const int lr = tid >> 4, lc = (tid & 15) * 4;
#pragma unroll
    for (int l = 0; l < 4; ++l) {
        const int row = lr + l * 16;
        const size_t gidx = bb + (size_t)(k0 + row) * 256 + i0 + lc;
        float4 n4 = *reinterpret_cast<const float4*>(nv + gidx);
        float4 e4 = *reinterpret_cast<const float4*>(ev + gidx);
        float4 x4 = *reinterpret_cast<const float4*>(x + gidx);
        TA[row][lc] = 0.5f * (n4.x + e4.x);
        TA[row][lc + 1] = 0.5f * (n4.y + e4.y);
        TA[row][lc + 2] = 0.5f * (n4.z + e4.z);
        TA[row][lc + 3] = 0.5f * (n4.w + e4.w);
        TX[row][lc] = x4.x;
        TX[row][lc + 1] = x4.y;
        TX[row][lc + 2] = x4.z;
        TX[row][lc + 3] = x4.w;
    }
    __syncthreads();
    const int i = tid & 63, kk = (tid >> 6) * 16;
    bfrag a0, a1, x0, x1;
#pragma unroll
    for (int e = 0; e < 8; ++e) {
        a0[e] = (short)f2bf(TA[kk + e][i]);
        a1[e] = (short)f2bf(TA[kk + 8 + e][i]);
        x0[e] = (short)f2bf(TX[kk + e][i]);
        x1[e] = (short)f2bf(TX[kk + 8 + e][i]);
    }
    const size_t o = bb + (size_t)(i0 + i) * 256 + k0 + kk;
    *reinterpret_cast<bfrag*>(At + o) = a0;
    *reinterpret_cast<bfrag*>(At + o + 8) = a1;
    *reinterpret_cast<bfrag*>(Xt + o) = x0;
    *reinterpret_cast<bfrag*>(Xt + o + 8) = x1;
}

// ---------------------------------------------------------------------------
// m97 GEMM core (BM=BN=128, BK=64, 4 waves, global_load_lds, linear LDS).
// ---------------------------------------------------------------------------
#define MM97_STAGE(SRC, LDS, KSTRIDE)                                        \
    {                                                                        \
        _Pragma("unroll")                                                    \
        for (int c = 0; c < 4; ++c) {                                        \
            const int rr = (w << 5) + (c << 3) + (lane >> 3);                \
            gll16(SRC + (size_t)rr * (KSTRIDE) + k0 + ((lane & 7) << 3),     \
                  LDS + (((w << 5) + (c << 3)) << 6));                       \
        }                                                                    \
    }

#define MM97_COMPUTE()                                                       \
    _Pragma("unroll")                                                        \
    for (int ks = 0; ks < 2; ++ks) {                                         \
        const int kb = ks * 32 + fq * 8;                                     \
        bfrag af[4], bfv[4];                                                 \
        _Pragma("unroll")                                                    \
        for (int fm = 0; fm < 4; ++fm)                                       \
            af[fm] = *reinterpret_cast<const bfrag*>(                        \
                &As[((wm * 64 + fm * 16 + fr) << 6) + kb]);                  \
        _Pragma("unroll")                                                    \
        for (int fn = 0; fn < 4; ++fn)                                       \
            bfv[fn] = *reinterpret_cast<const bfrag*>(                       \
                &Bs[((wn * 64 + fn * 16 + fr) << 6) + kb]);                  \
        _Pragma("unroll")                                                    \
        for (int fm = 0; fm < 4; ++fm)                                       \
            _Pragma("unroll")                                                \
            for (int fn = 0; fn < 4; ++fn)                                   \
                acc[fm][fn] = __builtin_amdgcn_mfma_f32_16x16x32_bf16(       \
                    bfv[fn], af[fm], acc[fm][fn], 0, 0, 0);                  \
    }

// ---------------------------------------------------------------------------
// Generic m97 GEMM. C = A * B^T (+bias). EPI: 0 none, 2 relu.
// grid (M/128, N/128, nbatch).
// ---------------------------------------------------------------------------
template <int EPI, bool WF32, bool WBF>
__global__ __launch_bounds__(256) void k_mm97(
    const ushort* __restrict__ A, const ushort* __restrict__ B,
    const float* __restrict__ bias, float* __restrict__ C,
    ushort* __restrict__ Cb, int K, int N,
    size_t aStr, size_t bStr, size_t cStr) {
    __shared__ __align__(16) ushort As[128 * 64];
    __shared__ __align__(16) ushort Bs[128 * 64];
    const int tid = threadIdx.x;
    const int m0 = blockIdx.x * 128, n0 = blockIdx.y * 128;
    const size_t z = blockIdx.z;
    const int w = tid >> 6, lane = tid & 63;
    const int wm = w >> 1, wn = w & 1;
    const int fr = lane & 15, fq = lane >> 4;

    const ushort* aB = A + z * aStr + (size_t)m0 * K;
    const ushort* bB = B + z * bStr + (size_t)n0 * K;

    f4_t acc[4][4];
#pragma unroll
    for (int i = 0; i < 4; ++i)
#pragma unroll
        for (int j = 0; j < 4; ++j) acc[i][j] = (f4_t)0.f;

    for (int k0 = 0; k0 < K; k0 += 64) {
        MM97_STAGE(aB, As, K)
        MM97_STAGE(bB, Bs, K)
        __syncthreads();
        MM97_COMPUTE()
        __syncthreads();
    }

#pragma unroll
    for (int fn = 0; fn < 4; ++fn) {
        const int col0 = n0 + wn * 64 + fn * 16 + fq * 4;
        float4 bv = make_float4(0.f, 0.f, 0.f, 0.f);
        if (bias != nullptr)
            bv = *reinterpret_cast<const float4*>(&bias[col0]);
#pragma unroll
        for (int fm = 0; fm < 4; ++fm) {
            const int row = m0 + wm * 64 + fm * 16 + fr;
            float v0 = acc[fm][fn][0] + bv.x;
            float v1 = acc[fm][fn][1] + bv.y;
            float v2 = acc[fm][fn][2] + bv.z;
            float v3 = acc[fm][fn][3] + bv.w;
            if (EPI == 2) {
                v0 = fmaxf(v0, 0.f); v1 = fmaxf(v1, 0.f);
                v2 = fmaxf(v2, 0.f); v3 = fmaxf(v3, 0.f);
            }
            const size_t o = cStr * z + (size_t)row * N + col0;
            if (WF32) {
                float4 fv = {v0, v1, v2, v3};
                *reinterpret_cast<float4*>(&C[o]) = fv;
            }
            if (WBF) {
                ushort4 uv;
                uv.x = f2bf(v0); uv.y = f2bf(v1);
                uv.z = f2bf(v2); uv.w = f2bf(v3);
                *reinterpret_cast<ushort4*>(&Cb[o]) = uv;
            }
        }
    }
}

// ---------------------------------------------------------------------------
// qkv GEMM (m97 core): epilogue writes head-blocked layouts.
// ---------------------------------------------------------------------------
__global__ __launch_bounds__(256) void k_mmqkv97(
    const ushort* __restrict__ A, const ushort* __restrict__ B,
    const float* __restrict__ bias, ushort* __restrict__ qb,
    ushort* __restrict__ kbuf, ushort* __restrict__ vtb) {
    __shared__ __align__(16) ushort As[128 * 64];
    __shared__ __align__(16) ushort Bs[128 * 64];
    const int tid = threadIdx.x;
    const int m0 = blockIdx.x * 128, n0 = blockIdx.y * 128;
    const int w = tid >> 6, lane = tid & 63;
    const int wm = w >> 1, wn = w & 1;
    const int fr = lane & 15, fq = lane >> 4;
    const int K = 256;

    const ushort* aB = A + (size_t)m0 * K;
    const ushort* bB = B + (size_t)n0 * K;

    f4_t acc[4][4];
#pragma unroll
    for (int i = 0; i < 4; ++i)
#pragma unroll
        for (int j = 0; j < 4; ++j) acc[i][j] = (f4_t)0.f;

    for (int k0 = 0; k0 < K; k0 += 64) {
        MM97_STAGE(aB, As, K)
        MM97_STAGE(bB, Bs, K)
        __syncthreads();
        MM97_COMPUTE()
        __syncthreads();
    }

    const int sec = n0 >> 8;  // 0=q, 1=k, 2=v
#pragma unroll
    for (int fn = 0; fn < 4; ++fn) {
        const int col0 = n0 + wn * 64 + fn * 16 + fq * 4;
        const int hd = (col0 >> 5) & 7, dq = col0 & 31;
        const float4 bv = *reinterpret_cast<const float4*>(&bias[col0]);
#pragma unroll
        for (int fm = 0; fm < 4; ++fm) {
            const int row = m0 + wm * 64 + fm * 16 + fr;
            const int b = row >> 8, t = row & 255;
            const size_t bh = (size_t)b * 8 + hd;
            float v0 = acc[fm][fn][0] + bv.x;
            float v1 = acc[fm][fn][1] + bv.y;
            float v2 = acc[fm][fn][2] + bv.z;
            float v3 = acc[fm][fn][3] + bv.w;
            if (sec < 2) {
                ushort4 uv;
                uv.x = f2bf(v0); uv.y = f2bf(v1);
                uv.z = f2bf(v2); uv.w = f2bf(v3);
                ushort* dst = (sec == 0 ? qb : kbuf) + (bh * 256 + t) * 32 + dq;
                *reinterpret_cast<ushort4*>(dst) = uv;
            } else {
                ushort* dst = vtb + (bh * 32 + dq) * 256 + t;
                dst[0] = f2bf(v0);
                dst[256] = f2bf(v1);
                dst[512] = f2bf(v2);
                dst[768] = f2bf(v3);
            }
        }
    }
}

// ---------------------------------------------------------------------------
// Fused corr-SYRK (blocks 0..255) + pool/heads (blocks 256..319).
// ---------------------------------------------------------------------------
__global__ __launch_bounds__(256) void k_corrpool(
    const ushort* __restrict__ yT, const float* __restrict__ stats,
    const ushort* __restrict__ h,
    const float* __restrict__ muw1, const float* __restrict__ mub1,
    const float* __restrict__ mug, const float* __restrict__ mubt,
    const float* __restrict__ muw2, const float* __restrict__ mub2,
    const float* __restrict__ lvw1, const float* __restrict__ lvb1,
    const float* __restrict__ lvg, const float* __restrict__ lvbt,
    const float* __restrict__ lvw2, const float* __restrict__ lvb2,
    float* __restrict__ out) {
    __shared__ __align__(16) ushort As[128 * 64];
    __shared__ __align__(16) ushort Bs[128 * 64];
    const int tid = threadIdx.x;
    const int vb = blockIdx.x;

    if (vb >= 256) {  // pool + heads for batch b
        const int b = vb - 256;
        float* pooled = (float*)As;        // reuse LDS
        float* rS = pooled + 256;
        float* rQ = rS + 4;
        float* t1 = rQ + 4;
        {
            const ushort* hb = h + (size_t)b * 65536 + tid;
            float s = 0.f;
            for (int t = 0; t < 256; ++t) s += bf2f(hb[(size_t)t * 256]);
            pooled[tid] = s * (1.f / 256.f);
        }
        __syncthreads();
        const int hd = tid >> 7, u = tid & 127;
        const float* w1 = hd ? lvw1 : muw1;
        const float* b1 = hd ? lvb1 : mub1;
        float a = b1[u];
        const float4* w1v = reinterpret_cast<const float4*>(w1 + (size_t)u * 256);
#pragma unroll 4
        for (int k4 = 0; k4 < 64; ++k4) {
            float4 wv = w1v[k4];
            float4 pv = *reinterpret_cast<const float4*>(&pooled[k4 * 4]);
            a = dot4(pv, wv, a);
        }
        float s = a, q = a * a;
#pragma unroll
        for (int m = 1; m < 64; m <<= 1) {
            s += __shfl_xor(s, m);
            q += __shfl_xor(q, m);
        }
        if ((tid & 63) == 0) { rS[tid >> 6] = s; rQ[tid >> 6] = q; }
        __syncthreads();
        {
            const float* g = hd ? lvg : mug;
            const float* bt = hd ? lvbt : mubt;
            const float S = rS[hd * 2] + rS[hd * 2 + 1];
            const float Q = rQ[hd * 2] + rQ[hd * 2 + 1];
            const float mean = S * (1.f / 128.f);
            const float var = Q * (1.f / 128.f) - mean * mean;
            const float rstd = rsqrtf(fmaxf(var, 0.f) + 1e-5f);
            float v = (a - mean) * rstd * g[u] + bt[u];
            v = v >= 0.f ? v : 0.1f * v;
            t1[hd * 128 + u] = v;
        }
        __syncthreads();
        if (tid < 128) {
            const int h2 = tid >> 6, ou = tid & 63;
            const float* w2 = h2 ? lvw2 : muw2;
            const float* b2 = h2 ? lvb2 : mub2;
            float o = b2[ou];
            const float* w2r = w2 + (size_t)ou * 128;
#pragma unroll 4
            for (int c = 0; c < 128; ++c) o = fmaf(t1[h2 * 128 + c], w2r[c], o);
            out[h2 * 4096 + b * 64 + ou] = o;
        }
        return;
    }

    // corr SYRK tile
    const int m0 = ((vb >> 1) & 1) * 128, n0 = (vb & 1) * 128;
    const size_t z = (size_t)(vb >> 2);
    const int w = tid >> 6, lane = tid & 63;
    const int wm = w >> 1, wn = w & 1;
    const int fr = lane & 15, fq = lane >> 4;
    const int K = 256;

    const ushort* aB = yT + z * 65536 + (size_t)m0 * K;
    const ushort* bB = yT + z * 65536 + (size_t)n0 * K;

    f4_t acc[4][4];
#pragma unroll
    for (int i = 0; i < 4; ++i)
#pragma unroll
        for (int j = 0; j < 4; ++j) acc[i][j] = (f4_t)0.f;

    for (int k0 = 0; k0 < K; k0 += 64) {
        MM97_STAGE(aB, As, K)
        MM97_STAGE(bB, Bs, K)
        __syncthreads();
        MM97_COMPUTE()
        __syncthreads();
    }

    const float* st = stats + z * 512;
    float* C = out + 8192;
#pragma unroll
    for (int fn = 0; fn < 4; ++fn) {
        const int col0 = n0 + wn * 64 + fn * 16 + fq * 4;
        const float4 muj = *reinterpret_cast<const float4*>(&st[col0]);
        const float4 isj = *reinterpret_cast<const float4*>(&st[256 + col0]);
#pragma unroll
        for (int fm = 0; fm < 4; ++fm) {
            const int row = m0 + wm * 64 + fm * 16 + fr;
            const float mui = st[row];
            const float isi = st[256 + row] * (1.f / 255.f);
            float v0 = (acc[fm][fn][0] - 256.f * mui * muj.x) * isi * isj.x;
            float v1 = (acc[fm][fn][1] - 256.f * mui * muj.y) * isi * isj.y;
            float v2 = (acc[fm][fn][2] - 256.f * mui * muj.z) * isi * isj.z;
            float v3 = (acc[fm][fn][3] - 256.f * mui * muj.w) * isi * isj.w;
            if (v0 != v0) v0 = 0.f;
            if (v1 != v1) v1 = 0.f;
            if (v2 != v2) v2 = 0.f;
            if (v3 != v3) v3 = 0.f;
            v0 = fminf(1.f, fmaxf(-1.f, v0));
            v1 = fminf(1.f, fmaxf(-1.f, v1));
            v2 = fminf(1.f, fmaxf(-1.f, v2));
            v3 = fminf(1.f, fmaxf(-1.f, v3));
            float4 fv = {v0, v1, v2, v3};
            *reinterpret_cast<float4*>(
                &C[z * 65536 + (size_t)row * 256 + col0]) = fv;
        }
    }
}

// ---------------------------------------------------------------------------
// Fused GEMM + bias (+bf16 residual) + LayerNorm(256) (+leaky) -> bf16 only.
// BM=32, BN=256=N, 256 threads = 4 waves; register prefetch.
// ---------------------------------------------------------------------------
template <int ACT, bool RES>
__global__ __launch_bounds__(256) void k_mmln(
    const ushort* __restrict__ A, const ushort* __restrict__ W,
    const float* __restrict__ bias, const ushort* __restrict__ res,
    const float* __restrict__ g, const float* __restrict__ bt,
    ushort* __restrict__ outb, int K) {
    __shared__ __align__(16) ushort As[32 * 72];
    __shared__ __align__(16) ushort Bs[256 * 72];
    __shared__ float redS[32][4];
    __shared__ float redQ[32][4];
    const int tid = threadIdx.x;
    const int m0 = blockIdx.x * 32;
    const int w = tid >> 6, lane = tid & 63;
    const int fr = lane & 15, fq = lane >> 4;

    const int arow = tid >> 3, akc = (tid & 7) * 8;
    const ushort* aS = A + (size_t)(m0 + arow) * K + akc;
    ushort* aD = &As[arow * 72 + akc];
    const int brow = tid >> 1, bkc = (tid & 1) * 32;
    const ushort* bS0 = W + (size_t)brow * K + bkc;
    const ushort* bS1 = W + (size_t)(brow + 128) * K + bkc;
    ushort* bD0 = &Bs[brow * 72 + bkc];
    ushort* bD1 = &Bs[(brow + 128) * 72 + bkc];

    f4_t acc[2][4];
#pragma unroll
    for (int i = 0; i < 2; ++i)
#pragma unroll
        for (int j = 0; j < 4; ++j) acc[i][j] = (f4_t)0.f;

    bfrag ra, rb0, rb1, rb2, rb3, rc0, rc1, rc2, rc3;
    {
        ra = *reinterpret_cast<const bfrag*>(aS);
        const bfrag* bp0 = reinterpret_cast<const bfrag*>(bS0);
        rb0 = bp0[0]; rb1 = bp0[1]; rb2 = bp0[2]; rb3 = bp0[3];
        const bfrag* bp1 = reinterpret_cast<const bfrag*>(bS1);
        rc0 = bp1[0]; rc1 = bp1[1]; rc2 = bp1[2]; rc3 = bp1[3];
    }

    for (int k0 = 0; k0 < K; k0 += 64) {
        *reinterpret_cast<bfrag*>(aD) = ra;
        reinterpret_cast<bfrag*>(bD0)[0] = rb0;
        reinterpret_cast<bfrag*>(bD0)[1] = rb1;
        reinterpret_cast<bfrag*>(bD0)[2] = rb2;
        reinterpret_cast<bfrag*>(bD0)[3] = rb3;
        reinterpret_cast<bfrag*>(bD1)[0] = rc0;
        reinterpret_cast<bfrag*>(bD1)[1] = rc1;
        reinterpret_cast<bfrag*>(bD1)[2] = rc2;
        reinterpret_cast<bfrag*>(bD1)[3] = rc3;
        __syncthreads();
        if (k0 + 64 < K) {
            ra = *reinterpret_cast<const bfrag*>(aS + k0 + 64);
            const bfrag* bp0 = reinterpret_cast<const bfrag*>(bS0 + k0 + 64);
            rb0 = bp0[0]; rb1 = bp0[1]; rb2 = bp0[2]; rb3 = bp0[3];
            const bfrag* bp1 = reinterpret_cast<const bfrag*>(bS1 + k0 + 64);
            rc0 = bp1[0]; rc1 = bp1[1]; rc2 = bp1[2]; rc3 = bp1[3];
        }
#pragma unroll
        for (int ks = 0; ks < 2; ++ks) {
            const int kb = ks * 32 + fq * 8;
            bfrag af[2], bf[4];
#pragma unroll
            for (int fm = 0; fm < 2; ++fm)
                af[fm] = *reinterpret_cast<const bfrag*>(
                    &As[(fm * 16 + fr) * 72 + kb]);
#pragma unroll
            for (int fn = 0; fn < 4; ++fn)
                bf[fn] = *reinterpret_cast<const bfrag*>(
                    &Bs[(w * 64 + fn * 16 + fr) * 72 + kb]);
#pragma unroll
            for (int fm = 0; fm < 2; ++fm)
#pragma unroll
                for (int fn = 0; fn < 4; ++fn)
                    acc[fm][fn] = __builtin_amdgcn_mfma_f32_16x16x32_bf16(
                        bf[fn], af[fm], acc[fm][fn], 0, 0, 0);
        }
        __syncthreads();
    }

#pragma unroll
    for (int fn = 0; fn < 4; ++fn) {
        const int col0 = w * 64 + fn * 16 + fq * 4;
        const float4 bv = *reinterpret_cast<const float4*>(&bias[col0]);
#pragma unroll
        for (int fm = 0; fm < 2; ++fm) {
            const int row = fm * 16 + fr;
            float r0 = 0.f, r1 = 0.f, r2 = 0.f, r3 = 0.f;
            if (RES) {
                ushort4 r4 = *reinterpret_cast<const ushort4*>(
                    &res[(size_t)(m0 + row) * 256 + col0]);
                r0 = bf2f(r4.x); r1 = bf2f(r4.y);
                r2 = bf2f(r4.z); r3 = bf2f(r4.w);
            }
            acc[fm][fn][0] += bv.x + r0;
            acc[fm][fn][1] += bv.y + r1;
            acc[fm][fn][2] += bv.z + r2;
            acc[fm][fn][3] += bv.w + r3;
        }
    }
#pragma unroll
    for (int fm = 0; fm < 2; ++fm) {
        float s = 0.f, q = 0.f;
#pragma unroll
        for (int fn = 0; fn < 4; ++fn)
#pragma unroll
            for (int j = 0; j < 4; ++j) {
                const float v = acc[fm][fn][j];
                s += v;
                q += v * v;
            }
        s += __shfl_xor(s, 16); q += __shfl_xor(q, 16);
        s += __shfl_xor(s, 32); q += __shfl_xor(q, 32);
        if (fq == 0) {
            redS[fm * 16 + fr][w] = s;
            redQ[fm * 16 + fr][w] = q;
        }
    }
    __syncthreads();
#pragma unroll
    for (int fm = 0; fm < 2; ++fm) {
        const int row = fm * 16 + fr;
        const float S = redS[row][0] + redS[row][1] + redS[row][2] + redS[row][3];
        const float Q = redQ[row][0] + redQ[row][1] + redQ[row][2] + redQ[row][3];
        const float mean = S * (1.f / 256.f);
        const float var = Q * (1.f / 256.f) - mean * mean;
        const float rstd = rsqrtf(fmaxf(var, 0.f) + 1e-5f);
        const size_t rowoff = (size_t)(m0 + row) * 256;
#pragma unroll
        for (int fn = 0; fn < 4; ++fn) {
            const int col0 = w * 64 + fn * 16 + fq * 4;
            const float4 g4 = *reinterpret_cast<const float4*>(&g[col0]);
            const float4 b4 = *reinterpret_cast<const float4*>(&bt[col0]);
            float v0 = (acc[fm][fn][0] - mean) * rstd * g4.x + b4.x;
            float v1 = (acc[fm][fn][1] - mean) * rstd * g4.y + b4.y;
            float v2 = (acc[fm][fn][2] - mean) * rstd * g4.z + b4.z;
            float v3 = (acc[fm][fn][3] - mean) * rstd * g4.w + b4.w;
            if (ACT == 1) {
                v0 = v0 >= 0.f ? v0 : 0.1f * v0;
                v1 = v1 >= 0.f ? v1 : 0.1f * v1;
                v2 = v2 >= 0.f ? v2 : 0.1f * v2;
                v3 = v3 >= 0.f ? v3 : 0.1f * v3;
            }
            ushort4 uv;
            uv.x = f2bf(v0); uv.y = f2bf(v1);
            uv.z = f2bf(v2); uv.w = f2bf(v3);
            *reinterpret_cast<ushort4*>(&outb[rowoff + col0]) = uv;
        }
    }
}

// ---------------------------------------------------------------------------
// Attention v3: Q/K from [b,h,t,32], V^T from [b,h,32,t]; LDS = P-bounce.
// ---------------------------------------------------------------------------
__global__ __launch_bounds__(256) void k_attn3(
    const ushort* __restrict__ qb, const ushort* __restrict__ kbuf,
    const ushort* __restrict__ vtb, ushort* __restrict__ o) {
    __shared__ __align__(16) ushort Ps[4][64][40];
    const int hd = blockIdx.x, b = blockIdx.y;
    const size_t bh = (size_t)b * 8 + hd;
    const int tid = threadIdx.x;
    const int w = tid >> 6, lane = tid & 63;
    const int fr = lane & 15, fq = lane >> 4;

    const ushort* qB = qb + bh * 8192;
    const ushort* kB = kbuf + bh * 8192;
    const ushort* vB = vtb + bh * 8192;

    const int q0 = w * 64;
    bfrag qf[4];
#pragma unroll
    for (int fm = 0; fm < 4; ++fm)
        qf[fm] = *reinterpret_cast<const bfrag*>(
            qB + (size_t)(q0 + fm * 16 + fr) * 32 + fq * 8);

    f4_t oacc[4][2];
    float rs[4][4];
#pragma unroll
    for (int fm = 0; fm < 4; ++fm) {
        oacc[fm][0] = (f4_t)0.f;
        oacc[fm][1] = (f4_t)0.f;
#pragma unroll
        for (int j = 0; j < 4; ++j) rs[fm][j] = 0.f;
    }
    const f4_t zero4 = (f4_t)0.f;
    const float qsl = 0.17677669529663687f * 1.4426950408889634f;

    for (int kt = 0; kt < 8; ++kt) {
        bfrag kf0 = *reinterpret_cast<const bfrag*>(
            kB + (size_t)(kt * 32 + fr) * 32 + fq * 8);
        bfrag kf1 = *reinterpret_cast<const bfrag*>(
            kB + (size_t)(kt * 32 + 16 + fr) * 32 + fq * 8);
        f4_t s0[4], s1[4];
#pragma unroll
        for (int fm = 0; fm < 4; ++fm) {
            s0[fm] = __builtin_amdgcn_mfma_f32_16x16x32_bf16(qf[fm], kf0, zero4, 0, 0, 0);
            s1[fm] = __builtin_amdgcn_mfma_f32_16x16x32_bf16(qf[fm], kf1, zero4, 0, 0, 0);
        }
#pragma unroll
        for (int fm = 0; fm < 4; ++fm) {
#pragma unroll
            for (int j = 0; j < 4; ++j) {
                const int row = fm * 16 + fq * 4 + j;
                ushort u0 = f2bf(exp2f(s0[fm][j] * qsl));
                ushort u1 = f2bf(exp2f(s1[fm][j] * qsl));
                Ps[w][row][fr] = u0;
                Ps[w][row][16 + fr] = u1;
                rs[fm][j] += bf2f(u0) + bf2f(u1);
            }
        }
        bfrag vf0 = *reinterpret_cast<const bfrag*>(
            vB + (size_t)fr * 256 + kt * 32 + fq * 8);
        bfrag vf1 = *reinterpret_cast<const bfrag*>(
            vB + (size_t)(16 + fr) * 256 + kt * 32 + fq * 8);
        bfrag pf[4];
#pragma unroll
        for (int fm = 0; fm < 4; ++fm)
            pf[fm] = *reinterpret_cast<const bfrag*>(&Ps[w][fm * 16 + fr][fq * 8]);
#pragma unroll
        for (int fm = 0; fm < 4; ++fm) {
            oacc[fm][0] = __builtin_amdgcn_mfma_f32_16x16x32_bf16(pf[fm], vf0, oacc[fm][0], 0, 0, 0);
            oacc[fm][1] = __builtin_amdgcn_mfma_f32_16x16x32_bf16(pf[fm], vf1, oacc[fm][1], 0, 0, 0);
        }
    }

#pragma unroll
    for (int fm = 0; fm < 4; ++fm)
#pragma unroll
        for (int j = 0; j < 4; ++j) {
            float r = rs[fm][j];
            r += __shfl_xor(r, 1);
            r += __shfl_xor(r, 2);
            r += __shfl_xor(r, 4);
            r += __shfl_xor(r, 8);
            rs[fm][j] = 1.f / r;
        }
    ushort* ob = o + (size_t)b * 65536 + hd * 32;
#pragma unroll
    for (int fm = 0; fm < 4; ++fm) {
        const int qrow = q0 + fm * 16 + fq * 4;
#pragma unroll
        for (int j = 0; j < 4; ++j) {
            const float inv = rs[fm][j];
            ob[(size_t)(qrow + j) * 256 + fr] = f2bf(oacc[fm][0][j] * inv);
            ob[(size_t)(qrow + j) * 256 + 16 + fr] = f2bf(oacc[fm][1][j] * inv);
        }
    }
}

// ---------------------------------------------------------------------------
// Row stats on yT[b][r][t]: mean, 1/(std+1e-8). grid (4, B), 256 threads.
// ---------------------------------------------------------------------------
__global__ __launch_bounds__(256) void k_rowstats(const ushort* __restrict__ yT,
                                                  float* __restrict__ stats) {
    const int b = blockIdx.y;
    const int r = blockIdx.x * 64 + (threadIdx.x >> 2);
    const int part = threadIdx.x & 3;
    const ushort* row = yT + (size_t)b * 65536 + (size_t)r * 256 + part * 64;
    float s = 0.f, q = 0.f;
#pragma unroll
    for (int i = 0; i < 8; ++i) {
        bfrag v = reinterpret_cast<const bfrag*>(row)[i];
#pragma unroll
        for (int e = 0; e < 8; ++e) {
            float f = bf2f((ushort)v[e]);
            s += f;
            q += f * f;
        }
    }
    s += __shfl_xor(s, 1); q += __shfl_xor(q, 1);
    s += __shfl_xor(s, 2); q += __shfl_xor(q, 2);
    if (part == 0) {
        const float mean = s * (1.f / 256.f);
        const float var = (q - s * mean) * (1.f / 255.f);
        const float stdv = sqrtf(fmaxf(var, 0.f));
        stats[b * 512 + r] = mean;
        stats[b * 512 + 256 + r] = 1.f / (stdv + 1e-8f);
    }
}

// ---------------------------------------------------------------------------
extern "C" void kernel_launch(void* const* d_in, const int* in_sizes, int n_in,
                              void* d_out, int out_size, void* d_ws, size_t ws_size,
                              hipStream_t stream) {
    const float* x = (const float*)d_in[0];
    const float* nv = (const float*)d_in[1];
    const float* ev = (const float*)d_in[2];
    const float* fp_w = (const float*)d_in[3];
    const float* fp_b = (const float*)d_in[4];
    const float* fp_g = (const float*)d_in[5];
    const float* fp_beta = (const float*)d_in[6];
    const float* qkv_w = (const float*)d_in[7];
    const float* qkv_b = (const float*)d_in[8];
    const float* aow = (const float*)d_in[9];
    const float* aob = (const float*)d_in[10];
    const float* ln1g = (const float*)d_in[11];
    const float* ln1b = (const float*)d_in[12];
    const float* f1w = (const float*)d_in[13];
    const float* f1b = (const float*)d_in[14];
    const float* f2w = (const float*)d_in[15];
    const float* f2b = (const float*)d_in[16];
    const float* ln2g = (const float*)d_in[17];
    const float* ln2b = (const float*)d_in[18];
    const float* outw = (const float*)d_in[19];
    const float* outb = (const float*)d_in[20];
    const float* muw1 = (const float*)d_in[21];
    const float* mub1 = (const float*)d_in[22];
    const float* mug = (const float*)d_in[23];
    const float* mubt = (const float*)d_in[24];
    const float* muw2 = (const float*)d_in[25];
    const float* mub2 = (const float*)d_in[26];
    const float* lvw1 = (const float*)d_in[27];
    const float* lvb1 = (const float*)d_in[28];
    const float* lvg = (const float*)d_in[29];
    const float* lvbt = (const float*)d_in[30];
    const float* lvw2 = (const float*)d_in[31];
    const float* lvb2 = (const float*)d_in[32];

    float* out = (float*)d_out;
    float* ws = (float*)d_ws;

    float* stats = ws;                     // [64][2][256]
    ushort* ub = (ushort*)(ws + 32768);
    ushort* wh_bf = ub;                    // [16384,256]
    ushort* At = ub + 4194304;             // [64,256,256]
    ushort* Xt = ub + 8388608;             // [64,256,256]
    ushort* o_bf = ub + 16777216;          // [16384,256]; h0_bf alias
    ushort* h0_bf = o_bf;
    ushort* f1_bf = ub + 20971520;         // [16384,512]
    ushort* qb = ub + 29360128;            // [64,8,256,32]
    ushort* kb = ub + 33554432;            // [64,8,256,32]
    ushort* vtb = ub + 37748736;           // [64,8,32,256]
    ushort* yT = ub + 41943040;            // [64,256,256]
    ushort* wbf = ub + 46137344;           // weights

    // 0+1a. weights cvt + input transpose (fused)
    k_prep<<<1600, 256, 0, stream>>>(x, nv, ev, fp_w, qkv_w, aow, f1w, f2w,
                                     outw, wbf, At, Xt);

    // 1b. message passing bmm -> h0_bf
    k_mm97<0, false, true><<<dim3(2, 2, BB), 256, 0, stream>>>(
        At, Xt, nullptr, nullptr, h0_bf, 256, 256, 65536, 65536, 65536);

    // 2. feature proj + LN + leaky -> wh_bf
    k_mmln<1, false><<<512, 256, 0, stream>>>(
        h0_bf, wbf, fp_b, nullptr, fp_g, fp_beta, wh_bf, 256);

    // 3. transformer layers
    for (int l = 0; l < NLAYER; ++l) {
        k_mmqkv97<<<dim3(128, 6), 256, 0, stream>>>(
            wh_bf, wbf + 65536 + (size_t)l * 196608, qkv_b + l * 768,
            qb, kb, vtb);
        k_attn3<<<dim3(8, BB), 256, 0, stream>>>(qb, kb, vtb, o_bf);
        k_mmln<0, true><<<512, 256, 0, stream>>>(
            o_bf, wbf + 458752 + (size_t)l * 65536, aob + l * 256,
            wh_bf, ln1g + l * 256, ln1b + l * 256, wh_bf, 256);
        k_mm97<2, false, true><<<dim3(128, 4, 1), 256, 0, stream>>>(
            wh_bf, wbf + 589824 + (size_t)l * 131072, f1b + l * 512,
            nullptr, f1_bf, 256, 512, 0, 0, 0);
        k_mmln<0, true><<<512, 256, 0, stream>>>(
            f1_bf, wbf + 851968 + (size_t)l * 131072, f2b + l * 256,
            wh_bf, ln2g + l * 256, ln2b + l * 256, wh_bf, 512);
    }

    // 4. yT = outw @ h^T (bias dropped: Pearson shift-invariant)
    k_mm97<0, false, true><<<dim3(2, 2, BB), 256, 0, stream>>>(
        wbf + 1114112, wh_bf, nullptr, nullptr, yT, 256, 256, 0, 65536, 65536);

    // 5. Pearson row stats
    k_rowstats<<<dim3(4, BB), 256, 0, stream>>>(yT, stats);

    // 6. corr SYRK + pool/heads (fused launch)
    k_corrpool<<<320, 256, 0, stream>>>(
        yT, stats, wh_bf, muw1, mub1, mug, mubt, muw2, mub2,
        lvw1, lvb1, lvg, lvbt, lvw2, lvb2, out);
}

// Round 15
// 227.412 us; speedup vs baseline: 1.1345x; 1.0079x over previous
//
#include <hip/hip_runtime.h>
#include <hip/hip_bf16.h>
#include <math.h>

#define BB 64
#define NLAYER 2

typedef __attribute__((ext_vector_type(8))) short bfrag;
typedef __attribute__((ext_vector_type(4))) float f4_t;

__device__ __forceinline__ float dot4(float4 a, float4 b, float acc) {
    acc = fmaf(a.x, b.x, acc);
    acc = fmaf(a.y, b.y, acc);
    acc = fmaf(a.z, b.z, acc);
    acc = fmaf(a.w, b.w, acc);
    return acc;
}

// fp32 -> bf16 round-to-nearest-even
__device__ __forceinline__ ushort f2bf(float f) {
    uint32_t u = __float_as_uint(f);
    uint32_t r = (u + 0x7FFFu + ((u >> 16) & 1u)) >> 16;
    return (ushort)r;
}
__device__ __forceinline__ float bf2f(ushort u) {
    return __uint_as_float(((uint32_t)u) << 16);
}

__device__ __forceinline__ void gll16(const ushort* g, ushort* l) {
    __builtin_amdgcn_global_load_lds(
        (const __attribute__((address_space(1))) void*)g,
        (__attribute__((address_space(3))) void*)l, 16, 0, 0);
}

// ---------------------------------------------------------------------------
// Fused prep: blocks 0..575 convert weights fp32->bf16; blocks 576..1599
// transpose+convert message-passing inputs.
// ---------------------------------------------------------------------------
__global__ __launch_bounds__(256) void k_prep(
    const float* __restrict__ x, const float* __restrict__ nv,
    const float* __restrict__ ev,
    const float* __restrict__ fp_w, const float* __restrict__ qkv_w,
    const float* __restrict__ aow, const float* __restrict__ f1w,
    const float* __restrict__ f2w, const float* __restrict__ outw,
    ushort* __restrict__ wbf, ushort* __restrict__ At,
    ushort* __restrict__ Xt) {
    const int vb = blockIdx.x;
    const int tid = threadIdx.x;
    if (vb < 576) {
        const int g = vb;
        const size_t idx = (size_t)g * 2048 + tid * 8;
        const float* src;
        size_t base;
        if (g < 32)       { src = fp_w;  base = 0; }
        else if (g < 224) { src = qkv_w; base = 65536; }
        else if (g < 288) { src = aow;   base = 458752; }
        else if (g < 416) { src = f1w;   base = 589824; }
        else if (g < 544) { src = f2w;   base = 851968; }
        else              { src = outw;  base = 1114112; }
        const float4* s4 = reinterpret_cast<const float4*>(src + (idx - base));
        float4 a = s4[0], b = s4[1];
        bfrag o;
        o[0] = (short)f2bf(a.x); o[1] = (short)f2bf(a.y);
        o[2] = (short)f2bf(a.z); o[3] = (short)f2bf(a.w);
        o[4] = (short)f2bf(b.x); o[5] = (short)f2bf(b.y);
        o[6] = (short)f2bf(b.z); o[7] = (short)f2bf(b.w);
        *reinterpret_cast<bfrag*>(wbf + idx) = o;
        return;
    }
    __shared__ float TA[64][65];
    __shared__ float TX[64][65];
    const int q = vb - 576;
    const int k0 = (q & 3) * 64, i0 = ((q >> 2) & 3) * 64, b = q >> 4;
    const size_t bb = (size_t)b * 65536;
    const int lr = tid >> 4, lc = (tid & 15) * 4;
#pragma unroll
    for (int l = 0; l < 4; ++l) {
        const int row = lr + l * 16;
        const size_t gidx = bb + (size_t)(k0 + row) * 256 + i0 + lc;
        float4 n4 = *reinterpret_cast<const float4*>(nv + gidx);
        float4 e4 = *reinterpret_cast<const float4*>(ev + gidx);
        float4 x4 = *reinterpret_cast<const float4*>(x + gidx);
        TA[row][lc] = 0.5f * (n4.x + e4.x);
        TA[row][lc + 1] = 0.5f * (n4.y + e4.y);
        TA[row][lc + 2] = 0.5f * (n4.z + e4.z);
        TA[row][lc + 3] = 0.5f * (n4.w + e4.w);
        TX[row][lc] = x4.x;
        TX[row][lc + 1] = x4.y;
        TX[row][lc + 2] = x4.z;
        TX[row][lc + 3] = x4.w;
    }
    __syncthreads();
    const int i = tid & 63, kk = (tid >> 6) * 16;
    bfrag a0, a1, x0, x1;
#pragma unroll
    for (int e = 0; e < 8; ++e) {
        a0[e] = (short)f2bf(TA[kk + e][i]);
        a1[e] = (short)f2bf(TA[kk + 8 + e][i]);
        x0[e] = (short)f2bf(TX[kk + e][i]);
        x1[e] = (short)f2bf(TX[kk + 8 + e][i]);
    }
    const size_t o = bb + (size_t)(i0 + i) * 256 + k0 + kk;
    *reinterpret_cast<bfrag*>(At + o) = a0;
    *reinterpret_cast<bfrag*>(At + o + 8) = a1;
    *reinterpret_cast<bfrag*>(Xt + o) = x0;
    *reinterpret_cast<bfrag*>(Xt + o + 8) = x1;
}

// ---------------------------------------------------------------------------
// m97 GEMM core (BM=BN=128, BK=64, 4 waves, global_load_lds, linear LDS).
// ---------------------------------------------------------------------------
#define MM97_STAGE(SRC, LDS, KSTRIDE)                                        \
    {                                                                        \
        _Pragma("unroll")                                                    \
        for (int c = 0; c < 4; ++c) {                                        \
            const int rr = (w << 5) + (c << 3) + (lane >> 3);                \
            gll16(SRC + (size_t)rr * (KSTRIDE) + k0 + ((lane & 7) << 3),     \
                  LDS + (((w << 5) + (c << 3)) << 6));                       \
        }                                                                    \
    }

#define MM97_COMPUTE()                                                       \
    _Pragma("unroll")                                                        \
    for (int ks = 0; ks < 2; ++ks) {                                         \
        const int kb = ks * 32 + fq * 8;                                     \
        bfrag af[4], bfv[4];                                                 \
        _Pragma("unroll")                                                    \
        for (int fm = 0; fm < 4; ++fm)                                       \
            af[fm] = *reinterpret_cast<const bfrag*>(                        \
                &As[((wm * 64 + fm * 16 + fr) << 6) + kb]);                  \
        _Pragma("unroll")                                                    \
        for (int fn = 0; fn < 4; ++fn)                                       \
            bfv[fn] = *reinterpret_cast<const bfrag*>(                       \
                &Bs[((wn * 64 + fn * 16 + fr) << 6) + kb]);                  \
        _Pragma("unroll")                                                    \
        for (int fm = 0; fm < 4; ++fm)                                       \
            _Pragma("unroll")                                                \
            for (int fn = 0; fn < 4; ++fn)                                   \
                acc[fm][fn] = __builtin_amdgcn_mfma_f32_16x16x32_bf16(       \
                    bfv[fn], af[fm], acc[fm][fn], 0, 0, 0);                  \
    }

// ---------------------------------------------------------------------------
// Generic m97 GEMM. C = A * B^T (+bias). EPI: 0 none, 2 relu.
// grid (M/128, N/128, nbatch).
// ---------------------------------------------------------------------------
template <int EPI, bool WF32, bool WBF>
__global__ __launch_bounds__(256) void k_mm97(
    const ushort* __restrict__ A, const ushort* __restrict__ B,
    const float* __restrict__ bias, float* __restrict__ C,
    ushort* __restrict__ Cb, int K, int N,
    size_t aStr, size_t bStr, size_t cStr) {
    __shared__ __align__(16) ushort As[128 * 64];
    __shared__ __align__(16) ushort Bs[128 * 64];
    const int tid = threadIdx.x;
    const int m0 = blockIdx.x * 128, n0 = blockIdx.y * 128;
    const size_t z = blockIdx.z;
    const int w = tid >> 6, lane = tid & 63;
    const int wm = w >> 1, wn = w & 1;
    const int fr = lane & 15, fq = lane >> 4;

    const ushort* aB = A + z * aStr + (size_t)m0 * K;
    const ushort* bB = B + z * bStr + (size_t)n0 * K;

    f4_t acc[4][4];
#pragma unroll
    for (int i = 0; i < 4; ++i)
#pragma unroll
        for (int j = 0; j < 4; ++j) acc[i][j] = (f4_t)0.f;

    for (int k0 = 0; k0 < K; k0 += 64) {
        MM97_STAGE(aB, As, K)
        MM97_STAGE(bB, Bs, K)
        __syncthreads();
        MM97_COMPUTE()
        __syncthreads();
    }

#pragma unroll
    for (int fn = 0; fn < 4; ++fn) {
        const int col0 = n0 + wn * 64 + fn * 16 + fq * 4;
        float4 bv = make_float4(0.f, 0.f, 0.f, 0.f);
        if (bias != nullptr)
            bv = *reinterpret_cast<const float4*>(&bias[col0]);
#pragma unroll
        for (int fm = 0; fm < 4; ++fm) {
            const int row = m0 + wm * 64 + fm * 16 + fr;
            float v0 = acc[fm][fn][0] + bv.x;
            float v1 = acc[fm][fn][1] + bv.y;
            float v2 = acc[fm][fn][2] + bv.z;
            float v3 = acc[fm][fn][3] + bv.w;
            if (EPI == 2) {
                v0 = fmaxf(v0, 0.f); v1 = fmaxf(v1, 0.f);
                v2 = fmaxf(v2, 0.f); v3 = fmaxf(v3, 0.f);
            }
            const size_t o = cStr * z + (size_t)row * N + col0;
            if (WF32) {
                float4 fv = {v0, v1, v2, v3};
                *reinterpret_cast<float4*>(&C[o]) = fv;
            }
            if (WBF) {
                ushort4 uv;
                uv.x = f2bf(v0); uv.y = f2bf(v1);
                uv.z = f2bf(v2); uv.w = f2bf(v3);
                *reinterpret_cast<ushort4*>(&Cb[o]) = uv;
            }
        }
    }
}

// ---------------------------------------------------------------------------
// qkv GEMM (m97 core): epilogue writes head-blocked layouts.
// ---------------------------------------------------------------------------
__global__ __launch_bounds__(256) void k_mmqkv97(
    const ushort* __restrict__ A, const ushort* __restrict__ B,
    const float* __restrict__ bias, ushort* __restrict__ qb,
    ushort* __restrict__ kbuf, ushort* __restrict__ vtb) {
    __shared__ __align__(16) ushort As[128 * 64];
    __shared__ __align__(16) ushort Bs[128 * 64];
    const int tid = threadIdx.x;
    const int m0 = blockIdx.x * 128, n0 = blockIdx.y * 128;
    const int w = tid >> 6, lane = tid & 63;
    const int wm = w >> 1, wn = w & 1;
    const int fr = lane & 15, fq = lane >> 4;
    const int K = 256;

    const ushort* aB = A + (size_t)m0 * K;
    const ushort* bB = B + (size_t)n0 * K;

    f4_t acc[4][4];
#pragma unroll
    for (int i = 0; i < 4; ++i)
#pragma unroll
        for (int j = 0; j < 4; ++j) acc[i][j] = (f4_t)0.f;

    for (int k0 = 0; k0 < K; k0 += 64) {
        MM97_STAGE(aB, As, K)
        MM97_STAGE(bB, Bs, K)
        __syncthreads();
        MM97_COMPUTE()
        __syncthreads();
    }

    const int sec = n0 >> 8;  // 0=q, 1=k, 2=v
#pragma unroll
    for (int fn = 0; fn < 4; ++fn) {
        const int col0 = n0 + wn * 64 + fn * 16 + fq * 4;
        const int hd = (col0 >> 5) & 7, dq = col0 & 31;
        const float4 bv = *reinterpret_cast<const float4*>(&bias[col0]);
#pragma unroll
        for (int fm = 0; fm < 4; ++fm) {
            const int row = m0 + wm * 64 + fm * 16 + fr;
            const int b = row >> 8, t = row & 255;
            const size_t bh = (size_t)b * 8 + hd;
            float v0 = acc[fm][fn][0] + bv.x;
            float v1 = acc[fm][fn][1] + bv.y;
            float v2 = acc[fm][fn][2] + bv.z;
            float v3 = acc[fm][fn][3] + bv.w;
            if (sec < 2) {
                ushort4 uv;
                uv.x = f2bf(v0); uv.y = f2bf(v1);
                uv.z = f2bf(v2); uv.w = f2bf(v3);
                ushort* dst = (sec == 0 ? qb : kbuf) + (bh * 256 + t) * 32 + dq;
                *reinterpret_cast<ushort4*>(dst) = uv;
            } else {
                ushort* dst = vtb + (bh * 32 + dq) * 256 + t;
                dst[0] = f2bf(v0);
                dst[256] = f2bf(v1);
                dst[512] = f2bf(v2);
                dst[768] = f2bf(v3);
            }
        }
    }
}

// ---------------------------------------------------------------------------
// Fused corr-SYRK with LOCAL row stats (blocks 0..255) + pool/heads
// (blocks 256..319). Stats computed per-block over the FULL 256-elem rows.
// ---------------------------------------------------------------------------
__global__ __launch_bounds__(256) void k_corrpool(
    const ushort* __restrict__ yT, const ushort* __restrict__ h,
    const float* __restrict__ muw1, const float* __restrict__ mub1,
    const float* __restrict__ mug, const float* __restrict__ mubt,
    const float* __restrict__ muw2, const float* __restrict__ mub2,
    const float* __restrict__ lvw1, const float* __restrict__ lvb1,
    const float* __restrict__ lvg, const float* __restrict__ lvbt,
    const float* __restrict__ lvw2, const float* __restrict__ lvb2,
    float* __restrict__ out) {
    __shared__ __align__(16) ushort As[128 * 64];
    __shared__ __align__(16) ushort Bs[128 * 64];
    __shared__ float sMu[256];   // [0..127]=m-rows, [128..255]=n-rows
    __shared__ float sIs[256];
    const int tid = threadIdx.x;
    const int vb = blockIdx.x;

    if (vb >= 256) {  // pool + heads for batch b
        const int b = vb - 256;
        float* pooled = (float*)As;
        float* rS = pooled + 256;
        float* rQ = rS + 4;
        float* t1 = rQ + 4;
        {
            const ushort* hb = h + (size_t)b * 65536 + tid;
            float s = 0.f;
            for (int t = 0; t < 256; ++t) s += bf2f(hb[(size_t)t * 256]);
            pooled[tid] = s * (1.f / 256.f);
        }
        __syncthreads();
        const int hd = tid >> 7, u = tid & 127;
        const float* w1 = hd ? lvw1 : muw1;
        const float* b1 = hd ? lvb1 : mub1;
        float a = b1[u];
        const float4* w1v = reinterpret_cast<const float4*>(w1 + (size_t)u * 256);
#pragma unroll 4
        for (int k4 = 0; k4 < 64; ++k4) {
            float4 wv = w1v[k4];
            float4 pv = *reinterpret_cast<const float4*>(&pooled[k4 * 4]);
            a = dot4(pv, wv, a);
        }
        float s = a, q = a * a;
#pragma unroll
        for (int m = 1; m < 64; m <<= 1) {
            s += __shfl_xor(s, m);
            q += __shfl_xor(q, m);
        }
        if ((tid & 63) == 0) { rS[tid >> 6] = s; rQ[tid >> 6] = q; }
        __syncthreads();
        {
            const float* g = hd ? lvg : mug;
            const float* bt = hd ? lvbt : mubt;
            const float S = rS[hd * 2] + rS[hd * 2 + 1];
            const float Q = rQ[hd * 2] + rQ[hd * 2 + 1];
            const float mean = S * (1.f / 128.f);
            const float var = Q * (1.f / 128.f) - mean * mean;
            const float rstd = rsqrtf(fmaxf(var, 0.f) + 1e-5f);
            float v = (a - mean) * rstd * g[u] + bt[u];
            v = v >= 0.f ? v : 0.1f * v;
            t1[hd * 128 + u] = v;
        }
        __syncthreads();
        if (tid < 128) {
            const int h2 = tid >> 6, ou = tid & 63;
            const float* w2 = h2 ? lvw2 : muw2;
            const float* b2 = h2 ? lvb2 : mub2;
            float o = b2[ou];
            const float* w2r = w2 + (size_t)ou * 128;
#pragma unroll 4
            for (int c = 0; c < 128; ++c) o = fmaf(t1[h2 * 128 + c], w2r[c], o);
            out[h2 * 4096 + b * 64 + ou] = o;
        }
        return;
    }

    // corr SYRK tile
    const int m0 = ((vb >> 1) & 1) * 128, n0 = (vb & 1) * 128;
    const size_t z = (size_t)(vb >> 2);
    const int w = tid >> 6, lane = tid & 63;
    const int wm = w >> 1, wn = w & 1;
    const int fr = lane & 15, fq = lane >> 4;
    const int K = 256;

    const ushort* yZ = yT + z * 65536;
    const ushort* aB = yZ + (size_t)m0 * K;
    const ushort* bB = yZ + (size_t)n0 * K;

    // local row stats: thread tid handles one full 256-elem row
    {
        const int row = (tid < 128) ? (m0 + tid) : (n0 + tid - 128);
        const bfrag* rp = reinterpret_cast<const bfrag*>(yZ + (size_t)row * 256);
        float s = 0.f, q = 0.f;
#pragma unroll 8
        for (int i = 0; i < 32; ++i) {
            bfrag v = rp[i];
#pragma unroll
            for (int e = 0; e < 8; ++e) {
                float f = bf2f((ushort)v[e]);
                s += f;
                q += f * f;
            }
        }
        const float mean = s * (1.f / 256.f);
        const float var = (q - s * mean) * (1.f / 255.f);
        const float stdv = sqrtf(fmaxf(var, 0.f));
        sMu[tid] = mean;
        sIs[tid] = 1.f / (stdv + 1e-8f);
    }

    f4_t acc[4][4];
#pragma unroll
    for (int i = 0; i < 4; ++i)
#pragma unroll
        for (int j = 0; j < 4; ++j) acc[i][j] = (f4_t)0.f;

    for (int k0 = 0; k0 < K; k0 += 64) {
        MM97_STAGE(aB, As, K)
        MM97_STAGE(bB, Bs, K)
        __syncthreads();
        MM97_COMPUTE()
        __syncthreads();
    }

    float* C = out + 8192;
#pragma unroll
    for (int fn = 0; fn < 4; ++fn) {
        const int cl0 = wn * 64 + fn * 16 + fq * 4;      // 0..127 in n-range
        const int col0 = n0 + cl0;
        const float4 muj = *reinterpret_cast<const float4*>(&sMu[128 + cl0]);
        const float4 isj = *reinterpret_cast<const float4*>(&sIs[128 + cl0]);
#pragma unroll
        for (int fm = 0; fm < 4; ++fm) {
            const int rl = wm * 64 + fm * 16 + fr;       // 0..127 in m-range
            const int row = m0 + rl;
            const float mui = sMu[rl];
            const float isi = sIs[rl] * (1.f / 255.f);
            float v0 = (acc[fm][fn][0] - 256.f * mui * muj.x) * isi * isj.x;
            float v1 = (acc[fm][fn][1] - 256.f * mui * muj.y) * isi * isj.y;
            float v2 = (acc[fm][fn][2] - 256.f * mui * muj.z) * isi * isj.z;
            float v3 = (acc[fm][fn][3] - 256.f * mui * muj.w) * isi * isj.w;
            if (v0 != v0) v0 = 0.f;
            if (v1 != v1) v1 = 0.f;
            if (v2 != v2) v2 = 0.f;
            if (v3 != v3) v3 = 0.f;
            v0 = fminf(1.f, fmaxf(-1.f, v0));
            v1 = fminf(1.f, fmaxf(-1.f, v1));
            v2 = fminf(1.f, fmaxf(-1.f, v2));
            v3 = fminf(1.f, fmaxf(-1.f, v3));
            float4 fv = {v0, v1, v2, v3};
            *reinterpret_cast<float4*>(
                &C[z * 65536 + (size_t)row * 256 + col0]) = fv;
        }
    }
}

// ---------------------------------------------------------------------------
// Fused GEMM + bias (+bf16 residual) + LayerNorm(256) (+leaky) -> bf16 only.
// BM=32, BN=256=N, 256 threads = 4 waves; register prefetch.
// ---------------------------------------------------------------------------
template <int ACT, bool RES>
__global__ __launch_bounds__(256) void k_mmln(
    const ushort* __restrict__ A, const ushort* __restrict__ W,
    const float* __restrict__ bias, const ushort* __restrict__ res,
    const float* __restrict__ g, const float* __restrict__ bt,
    ushort* __restrict__ outb, int K) {
    __shared__ __align__(16) ushort As[32 * 72];
    __shared__ __align__(16) ushort Bs[256 * 72];
    __shared__ float redS[32][4];
    __shared__ float redQ[32][4];
    const int tid = threadIdx.x;
    const int m0 = blockIdx.x * 32;
    const int w = tid >> 6, lane = tid & 63;
    const int fr = lane & 15, fq = lane >> 4;

    const int arow = tid >> 3, akc = (tid & 7) * 8;
    const ushort* aS = A + (size_t)(m0 + arow) * K + akc;
    ushort* aD = &As[arow * 72 + akc];
    const int brow = tid >> 1, bkc = (tid & 1) * 32;
    const ushort* bS0 = W + (size_t)brow * K + bkc;
    const ushort* bS1 = W + (size_t)(brow + 128) * K + bkc;
    ushort* bD0 = &Bs[brow * 72 + bkc];
    ushort* bD1 = &Bs[(brow + 128) * 72 + bkc];

    f4_t acc[2][4];
#pragma unroll
    for (int i = 0; i < 2; ++i)
#pragma unroll
        for (int j = 0; j < 4; ++j) acc[i][j] = (f4_t)0.f;

    bfrag ra, rb0, rb1, rb2, rb3, rc0, rc1, rc2, rc3;
    {
        ra = *reinterpret_cast<const bfrag*>(aS);
        const bfrag* bp0 = reinterpret_cast<const bfrag*>(bS0);
        rb0 = bp0[0]; rb1 = bp0[1]; rb2 = bp0[2]; rb3 = bp0[3];
        const bfrag* bp1 = reinterpret_cast<const bfrag*>(bS1);
        rc0 = bp1[0]; rc1 = bp1[1]; rc2 = bp1[2]; rc3 = bp1[3];
    }

    for (int k0 = 0; k0 < K; k0 += 64) {
        *reinterpret_cast<bfrag*>(aD) = ra;
        reinterpret_cast<bfrag*>(bD0)[0] = rb0;
        reinterpret_cast<bfrag*>(bD0)[1] = rb1;
        reinterpret_cast<bfrag*>(bD0)[2] = rb2;
        reinterpret_cast<bfrag*>(bD0)[3] = rb3;
        reinterpret_cast<bfrag*>(bD1)[0] = rc0;
        reinterpret_cast<bfrag*>(bD1)[1] = rc1;
        reinterpret_cast<bfrag*>(bD1)[2] = rc2;
        reinterpret_cast<bfrag*>(bD1)[3] = rc3;
        __syncthreads();
        if (k0 + 64 < K) {
            ra = *reinterpret_cast<const bfrag*>(aS + k0 + 64);
            const bfrag* bp0 = reinterpret_cast<const bfrag*>(bS0 + k0 + 64);
            rb0 = bp0[0]; rb1 = bp0[1]; rb2 = bp0[2]; rb3 = bp0[3];
            const bfrag* bp1 = reinterpret_cast<const bfrag*>(bS1 + k0 + 64);
            rc0 = bp1[0]; rc1 = bp1[1]; rc2 = bp1[2]; rc3 = bp1[3];
        }
#pragma unroll
        for (int ks = 0; ks < 2; ++ks) {
            const int kb = ks * 32 + fq * 8;
            bfrag af[2], bf[4];
#pragma unroll
            for (int fm = 0; fm < 2; ++fm)
                af[fm] = *reinterpret_cast<const bfrag*>(
                    &As[(fm * 16 + fr) * 72 + kb]);
#pragma unroll
            for (int fn = 0; fn < 4; ++fn)
                bf[fn] = *reinterpret_cast<const bfrag*>(
                    &Bs[(w * 64 + fn * 16 + fr) * 72 + kb]);
#pragma unroll
            for (int fm = 0; fm < 2; ++fm)
#pragma unroll
                for (int fn = 0; fn < 4; ++fn)
                    acc[fm][fn] = __builtin_amdgcn_mfma_f32_16x16x32_bf16(
                        bf[fn], af[fm], acc[fm][fn], 0, 0, 0);
        }
        __syncthreads();
    }

#pragma unroll
    for (int fn = 0; fn < 4; ++fn) {
        const int col0 = w * 64 + fn * 16 + fq * 4;
        const float4 bv = *reinterpret_cast<const float4*>(&bias[col0]);
#pragma unroll
        for (int fm = 0; fm < 2; ++fm) {
            const int row = fm * 16 + fr;
            float r0 = 0.f, r1 = 0.f, r2 = 0.f, r3 = 0.f;
            if (RES) {
                ushort4 r4 = *reinterpret_cast<const ushort4*>(
                    &res[(size_t)(m0 + row) * 256 + col0]);
                r0 = bf2f(r4.x); r1 = bf2f(r4.y);
                r2 = bf2f(r4.z); r3 = bf2f(r4.w);
            }
            acc[fm][fn][0] += bv.x + r0;
            acc[fm][fn][1] += bv.y + r1;
            acc[fm][fn][2] += bv.z + r2;
            acc[fm][fn][3] += bv.w + r3;
        }
    }
#pragma unroll
    for (int fm = 0; fm < 2; ++fm) {
        float s = 0.f, q = 0.f;
#pragma unroll
        for (int fn = 0; fn < 4; ++fn)
#pragma unroll
            for (int j = 0; j < 4; ++j) {
                const float v = acc[fm][fn][j];
                s += v;
                q += v * v;
            }
        s += __shfl_xor(s, 16); q += __shfl_xor(q, 16);
        s += __shfl_xor(s, 32); q += __shfl_xor(q, 32);
        if (fq == 0) {
            redS[fm * 16 + fr][w] = s;
            redQ[fm * 16 + fr][w] = q;
        }
    }
    __syncthreads();
#pragma unroll
    for (int fm = 0; fm < 2; ++fm) {
        const int row = fm * 16 + fr;
        const float S = redS[row][0] + redS[row][1] + redS[row][2] + redS[row][3];
        const float Q = redQ[row][0] + redQ[row][1] + redQ[row][2] + redQ[row][3];
        const float mean = S * (1.f / 256.f);
        const float var = Q * (1.f / 256.f) - mean * mean;
        const float rstd = rsqrtf(fmaxf(var, 0.f) + 1e-5f);
        const size_t rowoff = (size_t)(m0 + row) * 256;
#pragma unroll
        for (int fn = 0; fn < 4; ++fn) {
            const int col0 = w * 64 + fn * 16 + fq * 4;
            const float4 g4 = *reinterpret_cast<const float4*>(&g[col0]);
            const float4 b4 = *reinterpret_cast<const float4*>(&bt[col0]);
            float v0 = (acc[fm][fn][0] - mean) * rstd * g4.x + b4.x;
            float v1 = (acc[fm][fn][1] - mean) * rstd * g4.y + b4.y;
            float v2 = (acc[fm][fn][2] - mean) * rstd * g4.z + b4.z;
            float v3 = (acc[fm][fn][3] - mean) * rstd * g4.w + b4.w;
            if (ACT == 1) {
                v0 = v0 >= 0.f ? v0 : 0.1f * v0;
                v1 = v1 >= 0.f ? v1 : 0.1f * v1;
                v2 = v2 >= 0.f ? v2 : 0.1f * v2;
                v3 = v3 >= 0.f ? v3 : 0.1f * v3;
            }
            ushort4 uv;
            uv.x = f2bf(v0); uv.y = f2bf(v1);
            uv.z = f2bf(v2); uv.w = f2bf(v3);
            *reinterpret_cast<ushort4*>(&outb[rowoff + col0]) = uv;
        }
    }
}

// ---------------------------------------------------------------------------
// Attention v3: Q/K from [b,h,t,32], V^T from [b,h,32,t]; LDS = P-bounce.
// ---------------------------------------------------------------------------
__global__ __launch_bounds__(256) void k_attn3(
    const ushort* __restrict__ qb, const ushort* __restrict__ kbuf,
    const ushort* __restrict__ vtb, ushort* __restrict__ o) {
    __shared__ __align__(16) ushort Ps[4][64][40];
    const int hd = blockIdx.x, b = blockIdx.y;
    const size_t bh = (size_t)b * 8 + hd;
    const int tid = threadIdx.x;
    const int w = tid >> 6, lane = tid & 63;
    const int fr = lane & 15, fq = lane >> 4;

    const ushort* qB = qb + bh * 8192;
    const ushort* kB = kbuf + bh * 8192;
    const ushort* vB = vtb + bh * 8192;

    const int q0 = w * 64;
    bfrag qf[4];
#pragma unroll
    for (int fm = 0; fm < 4; ++fm)
        qf[fm] = *reinterpret_cast<const bfrag*>(
            qB + (size_t)(q0 + fm * 16 + fr) * 32 + fq * 8);

    f4_t oacc[4][2];
    float rs[4][4];
#pragma unroll
    for (int fm = 0; fm < 4; ++fm) {
        oacc[fm][0] = (f4_t)0.f;
        oacc[fm][1] = (f4_t)0.f;
#pragma unroll
        for (int j = 0; j < 4; ++j) rs[fm][j] = 0.f;
    }
    const f4_t zero4 = (f4_t)0.f;
    const float qsl = 0.17677669529663687f * 1.4426950408889634f;

    for (int kt = 0; kt < 8; ++kt) {
        bfrag kf0 = *reinterpret_cast<const bfrag*>(
            kB + (size_t)(kt * 32 + fr) * 32 + fq * 8);
        bfrag kf1 = *reinterpret_cast<const bfrag*>(
            kB + (size_t)(kt * 32 + 16 + fr) * 32 + fq * 8);
        f4_t s0[4], s1[4];
#pragma unroll
        for (int fm = 0; fm < 4; ++fm) {
            s0[fm] = __builtin_amdgcn_mfma_f32_16x16x32_bf16(qf[fm], kf0, zero4, 0, 0, 0);
            s1[fm] = __builtin_amdgcn_mfma_f32_16x16x32_bf16(qf[fm], kf1, zero4, 0, 0, 0);
        }
#pragma unroll
        for (int fm = 0; fm < 4; ++fm) {
#pragma unroll
            for (int j = 0; j < 4; ++j) {
                const int row = fm * 16 + fq * 4 + j;
                ushort u0 = f2bf(exp2f(s0[fm][j] * qsl));
                ushort u1 = f2bf(exp2f(s1[fm][j] * qsl));
                Ps[w][row][fr] = u0;
                Ps[w][row][16 + fr] = u1;
                rs[fm][j] += bf2f(u0) + bf2f(u1);
            }
        }
        bfrag vf0 = *reinterpret_cast<const bfrag*>(
            vB + (size_t)fr * 256 + kt * 32 + fq * 8);
        bfrag vf1 = *reinterpret_cast<const bfrag*>(
            vB + (size_t)(16 + fr) * 256 + kt * 32 + fq * 8);
        bfrag pf[4];
#pragma unroll
        for (int fm = 0; fm < 4; ++fm)
            pf[fm] = *reinterpret_cast<const bfrag*>(&Ps[w][fm * 16 + fr][fq * 8]);
#pragma unroll
        for (int fm = 0; fm < 4; ++fm) {
            oacc[fm][0] = __builtin_amdgcn_mfma_f32_16x16x32_bf16(pf[fm], vf0, oacc[fm][0], 0, 0, 0);
            oacc[fm][1] = __builtin_amdgcn_mfma_f32_16x16x32_bf16(pf[fm], vf1, oacc[fm][1], 0, 0, 0);
        }
    }

#pragma unroll
    for (int fm = 0; fm < 4; ++fm)
#pragma unroll
        for (int j = 0; j < 4; ++j) {
            float r = rs[fm][j];
            r += __shfl_xor(r, 1);
            r += __shfl_xor(r, 2);
            r += __shfl_xor(r, 4);
            r += __shfl_xor(r, 8);
            rs[fm][j] = 1.f / r;
        }
    ushort* ob = o + (size_t)b * 65536 + hd * 32;
#pragma unroll
    for (int fm = 0; fm < 4; ++fm) {
        const int qrow = q0 + fm * 16 + fq * 4;
#pragma unroll
        for (int j = 0; j < 4; ++j) {
            const float inv = rs[fm][j];
            ob[(size_t)(qrow + j) * 256 + fr] = f2bf(oacc[fm][0][j] * inv);
            ob[(size_t)(qrow + j) * 256 + 16 + fr] = f2bf(oacc[fm][1][j] * inv);
        }
    }
}

// ---------------------------------------------------------------------------
extern "C" void kernel_launch(void* const* d_in, const int* in_sizes, int n_in,
                              void* d_out, int out_size, void* d_ws, size_t ws_size,
                              hipStream_t stream) {
    const float* x = (const float*)d_in[0];
    const float* nv = (const float*)d_in[1];
    const float* ev = (const float*)d_in[2];
    const float* fp_w = (const float*)d_in[3];
    const float* fp_b = (const float*)d_in[4];
    const float* fp_g = (const float*)d_in[5];
    const float* fp_beta = (const float*)d_in[6];
    const float* qkv_w = (const float*)d_in[7];
    const float* qkv_b = (const float*)d_in[8];
    const float* aow = (const float*)d_in[9];
    const float* aob = (const float*)d_in[10];
    const float* ln1g = (const float*)d_in[11];
    const float* ln1b = (const float*)d_in[12];
    const float* f1w = (const float*)d_in[13];
    const float* f1b = (const float*)d_in[14];
    const float* f2w = (const float*)d_in[15];
    const float* f2b = (const float*)d_in[16];
    const float* ln2g = (const float*)d_in[17];
    const float* ln2b = (const float*)d_in[18];
    const float* outw = (const float*)d_in[19];
    const float* outb = (const float*)d_in[20];
    const float* muw1 = (const float*)d_in[21];
    const float* mub1 = (const float*)d_in[22];
    const float* mug = (const float*)d_in[23];
    const float* mubt = (const float*)d_in[24];
    const float* muw2 = (const float*)d_in[25];
    const float* mub2 = (const float*)d_in[26];
    const float* lvw1 = (const float*)d_in[27];
    const float* lvb1 = (const float*)d_in[28];
    const float* lvg = (const float*)d_in[29];
    const float* lvbt = (const float*)d_in[30];
    const float* lvw2 = (const float*)d_in[31];
    const float* lvb2 = (const float*)d_in[32];

    float* out = (float*)d_out;
    float* ws = (float*)d_ws;

    ushort* ub = (ushort*)ws;
    ushort* wh_bf = ub;                    // [16384,256]
    ushort* At = ub + 4194304;             // [64,256,256]
    ushort* Xt = ub + 8388608;             // [64,256,256]
    ushort* o_bf = ub + 16777216;          // [16384,256]; h0_bf alias
    ushort* h0_bf = o_bf;
    ushort* f1_bf = ub + 20971520;         // [16384,512]
    ushort* qb = ub + 29360128;            // [64,8,256,32]
    ushort* kb = ub + 33554432;            // [64,8,256,32]
    ushort* vtb = ub + 37748736;           // [64,8,32,256]
    ushort* yT = ub + 41943040;            // [64,256,256]
    ushort* wbf = ub + 46137344;           // weights

    // 0+1a. weights cvt + input transpose (fused)
    k_prep<<<1600, 256, 0, stream>>>(x, nv, ev, fp_w, qkv_w, aow, f1w, f2w,
                                     outw, wbf, At, Xt);

    // 1b. message passing bmm -> h0_bf
    k_mm97<0, false, true><<<dim3(2, 2, BB), 256, 0, stream>>>(
        At, Xt, nullptr, nullptr, h0_bf, 256, 256, 65536, 65536, 65536);

    // 2. feature proj + LN + leaky -> wh_bf
    k_mmln<1, false><<<512, 256, 0, stream>>>(
        h0_bf, wbf, fp_b, nullptr, fp_g, fp_beta, wh_bf, 256);

    // 3. transformer layers
    for (int l = 0; l < NLAYER; ++l) {
        k_mmqkv97<<<dim3(128, 6), 256, 0, stream>>>(
            wh_bf, wbf + 65536 + (size_t)l * 196608, qkv_b + l * 768,
            qb, kb, vtb);
        k_attn3<<<dim3(8, BB), 256, 0, stream>>>(qb, kb, vtb, o_bf);
        k_mmln<0, true><<<512, 256, 0, stream>>>(
            o_bf, wbf + 458752 + (size_t)l * 65536, aob + l * 256,
            wh_bf, ln1g + l * 256, ln1b + l * 256, wh_bf, 256);
        k_mm97<2, false, true><<<dim3(128, 4, 1), 256, 0, stream>>>(
            wh_bf, wbf + 589824 + (size_t)l * 131072, f1b + l * 512,
            nullptr, f1_bf, 256, 512, 0, 0, 0);
        k_mmln<0, true><<<512, 256, 0, stream>>>(
            f1_bf, wbf + 851968 + (size_t)l * 131072, f2b + l * 256,
            wh_bf, ln2g + l * 256, ln2b + l * 256, wh_bf, 512);
    }

    // 4. yT = outw @ h^T (bias dropped: Pearson shift-invariant)
    k_mm97<0, false, true><<<dim3(2, 2, BB), 256, 0, stream>>>(
        wbf + 1114112, wh_bf, nullptr, nullptr, yT, 256, 256, 0, 65536, 65536);

    // 5. corr SYRK (with local row stats) + pool/heads (fused launch)
    k_corrpool<<<320, 256, 0, stream>>>(
        yT, wh_bf, muw1, mub1, mug, mubt, muw2, mub2,
        lvw1, lvb1, lvg, lvbt, lvw2, lvb2, out);
}